// Round 2
// baseline (2097.057 us; speedup 1.0000x reference)
//
#include <hip/hip_runtime.h>
#include <hip/hip_bf16.h>

#define N_NODES 100000
#define NCLASS  64
#define NEDGE   1600000
#define NHID    256
#define TOPK    16
#define DEGREE  9

#define TM 16  // rows per block in MLP

__device__ __forceinline__ float fast_tanh(float x) {
    // tanh(x) = 1 - 2/(e^{2x}+1); saturates correctly at +/-inf
    float e = __expf(2.0f * x);
    return 1.0f - 2.0f / (e + 1.0f);
}

// ---------------- CSR build ----------------

__global__ void hist_kernel(const int* __restrict__ rows, int* __restrict__ counts, int e) {
    for (int i = blockIdx.x * blockDim.x + threadIdx.x; i < e; i += gridDim.x * blockDim.x)
        atomicAdd(&counts[rows[i]], 1);
}

__global__ __launch_bounds__(1024) void scan_blocks(const int* __restrict__ counts,
                                                    int* __restrict__ partial,
                                                    int* __restrict__ blocksums, int n) {
    __shared__ int s[1024];
    int tid = threadIdx.x;
    int gid = blockIdx.x * 1024 + tid;
    int v = (gid < n) ? counts[gid] : 0;
    s[tid] = v;
    __syncthreads();
    for (int off = 1; off < 1024; off <<= 1) {
        int t = (tid >= off) ? s[tid - off] : 0;
        __syncthreads();
        s[tid] += t;
        __syncthreads();
    }
    if (gid < n) partial[gid] = s[tid] - v;  // exclusive
    if (tid == 1023) blocksums[blockIdx.x] = s[1023];
}

__global__ void scan_sums(int* __restrict__ blocksums, int nb) {
    if (blockIdx.x == 0 && threadIdx.x == 0) {
        int run = 0;
        for (int i = 0; i < nb; ++i) { int v = blocksums[i]; blocksums[i] = run; run += v; }
    }
}

__global__ void finalize_rows(const int* __restrict__ partial, const int* __restrict__ blocksums,
                              int* __restrict__ row_start, int* __restrict__ cursor, int n, int e) {
    int i = blockIdx.x * blockDim.x + threadIdx.x;
    if (i < n) {
        int v = partial[i] + blocksums[i >> 10];
        row_start[i] = v;
        cursor[i] = v;
    }
    if (i == 0) row_start[n] = e;
}

__global__ void scatter_edges(const int* __restrict__ rows, const int* __restrict__ cols,
                              const float* __restrict__ vals, int* __restrict__ cursor,
                              int2* __restrict__ sedge, int e) {
    for (int i = blockIdx.x * blockDim.x + threadIdx.x; i < e; i += gridDim.x * blockDim.x) {
        int r = rows[i];
        int pos = atomicAdd(&cursor[r], 1);
        sedge[pos] = make_int2(cols[i], __float_as_int(vals[i]));
    }
}

// ---------------- softmax + top-16 (wave per row) ----------------

__global__ __launch_bounds__(256) void softmax_topk(const float* __restrict__ g0,
                                                    float* __restrict__ ranked, int n) {
    int wave = (blockIdx.x * 256 + threadIdx.x) >> 6;
    int lane = threadIdx.x & 63;
    if (wave >= n) return;
    float x = g0[(size_t)wave * NCLASS + lane];
    float m = x;
    #pragma unroll
    for (int o = 1; o < 64; o <<= 1) m = fmaxf(m, __shfl_xor(m, o));
    float p = expf(x - m);
    float s = p;
    #pragma unroll
    for (int o = 1; o < 64; o <<= 1) s += __shfl_xor(s, o);
    p /= s;
    // bitonic sort 64 lanes, descending (lane 0 = max)
    float v = p;
    #pragma unroll
    for (int k = 2; k <= 64; k <<= 1) {
        #pragma unroll
        for (int j = k >> 1; j > 0; j >>= 1) {
            float o = __shfl_xor(v, j);
            bool up = (lane & k) != 0;
            bool takeMax = (((lane & j) == 0) != up);
            v = takeMax ? fmaxf(v, o) : fminf(v, o);
        }
    }
    if (lane < TOPK) ranked[wave * TOPK + lane] = v;
}

// ---------------- MLP: [N,16] -> 512 -> 256 -> 9 ----------------

__global__ __launch_bounds__(256) void mlp_kernel(const float* __restrict__ ranked,
                                                  const float* __restrict__ W1, const float* __restrict__ b1,
                                                  const float* __restrict__ W2, const float* __restrict__ b2,
                                                  const float* __restrict__ W3, const float* __restrict__ b3,
                                                  float* __restrict__ weight_out, int n) {
    __shared__ float s_rank[TM][TOPK];
    __shared__ float s_h1[TM][2 * NHID];   // 32 KB
    __shared__ float s_h2[TM][NHID];       // 16 KB
    int t = threadIdx.x;
    int row0 = blockIdx.x * TM;

    // load ranked tile (TM*16 = 256 elements)
    {
        int r = t >> 4, k = t & 15;
        int gr = row0 + r;
        s_rank[r][k] = (gr < n) ? ranked[gr * TOPK + k] : 0.0f;
    }
    __syncthreads();

    // layer 1: TM x 512 outputs, 32 per thread
    #pragma unroll
    for (int i = 0; i < TM * 2 * NHID / 256; ++i) {
        int idx = i * 256 + t;
        int r = idx >> 9, j = idx & 511;
        float acc = b1[j];
        #pragma unroll
        for (int k = 0; k < TOPK; ++k) acc += s_rank[r][k] * W1[k * (2 * NHID) + j];
        s_h1[r][j] = fast_tanh(acc);
    }
    __syncthreads();

    // layer 2: each thread owns column c = t, TM row accumulators
    {
        float acc[TM];
        float bias2 = b2[t];
        #pragma unroll
        for (int r = 0; r < TM; ++r) acc[r] = bias2;
        for (int k = 0; k < 2 * NHID; k += 4) {
            float w0 = W2[(k + 0) * NHID + t];
            float w1 = W2[(k + 1) * NHID + t];
            float w2_ = W2[(k + 2) * NHID + t];
            float w3_ = W2[(k + 3) * NHID + t];
            #pragma unroll
            for (int r = 0; r < TM; ++r) {
                float4 h = *reinterpret_cast<const float4*>(&s_h1[r][k]);  // broadcast
                acc[r] += h.x * w0 + h.y * w1 + h.z * w2_ + h.w * w3_;
            }
        }
        #pragma unroll
        for (int r = 0; r < TM; ++r) s_h2[r][t] = fast_tanh(acc[r]);
    }
    __syncthreads();

    // layer 3: TM x 9 = 144 outputs
    if (t < TM * DEGREE) {
        int r = t / DEGREE, d = t % DEGREE;
        float acc = b3[d];
        for (int k = 0; k < NHID; ++k) acc += s_h2[r][k] * W3[k * DEGREE + d];
        int gr = row0 + r;
        if (gr < n) weight_out[gr * DEGREE + d] = acc;
    }
}

// ---------------- final init + SpMM chain ----------------

__global__ void init_final(const float* __restrict__ fpred, const float* __restrict__ weight,
                           float* __restrict__ finalbuf, int n) {
    int i = blockIdx.x * blockDim.x + threadIdx.x;
    if (i < n * NCLASS) {
        int row = i >> 6;
        finalbuf[i] = weight[row * DEGREE] * fpred[i];
    }
}

__global__ __launch_bounds__(256) void spmm_fused(const int* __restrict__ row_start,
                                                  const int2* __restrict__ sedge,
                                                  const float* __restrict__ x,
                                                  float* __restrict__ y,
                                                  const float* __restrict__ weight,
                                                  float* __restrict__ finalbuf,
                                                  int wcol, int n) {
    int wave = (blockIdx.x * 256 + threadIdx.x) >> 6;
    int lane = threadIdx.x & 63;
    if (wave >= n) return;
    int e0 = row_start[wave], e1 = row_start[wave + 1];
    float acc = 0.0f;
    int2 ef = (e0 < e1) ? sedge[e0] : make_int2(0, 0);
    for (int e = e0; e < e1; ++e) {
        int2 cur = ef;
        if (e + 1 < e1) ef = sedge[e + 1];           // prefetch next edge
        acc += __int_as_float(cur.y) * x[cur.x * NCLASS + lane];
    }
    int o = wave * NCLASS + lane;
    y[o] = acc;
    finalbuf[o] += weight[wave * DEGREE + wcol] * acc;
}

__global__ __launch_bounds__(256) void logsoftmax_inplace(float* __restrict__ out, int n) {
    int wave = (blockIdx.x * 256 + threadIdx.x) >> 6;
    int lane = threadIdx.x & 63;
    if (wave >= n) return;
    int o = wave * NCLASS + lane;
    float x = out[o];
    float m = x;
    #pragma unroll
    for (int off = 1; off < 64; off <<= 1) m = fmaxf(m, __shfl_xor(m, off));
    float p = expf(x - m);
    float s = p;
    #pragma unroll
    for (int off = 1; off < 64; off <<= 1) s += __shfl_xor(s, off);
    out[o] = x - m - logf(s);
}

// ---------------- launch ----------------

extern "C" void kernel_launch(void* const* d_in, const int* in_sizes, int n_in,
                              void* d_out, int out_size, void* d_ws, size_t ws_size,
                              hipStream_t stream) {
    const float* f_pred = (const float*)d_in[0];
    const float* g0     = (const float*)d_in[1];
    const int*   arows  = (const int*)d_in[2];
    const int*   acols  = (const int*)d_in[3];
    const float* avals  = (const float*)d_in[4];
    const float* W1     = (const float*)d_in[5];
    const float* b1     = (const float*)d_in[6];
    const float* W2     = (const float*)d_in[7];
    const float* b2     = (const float*)d_in[8];
    const float* W3     = (const float*)d_in[9];
    const float* b3     = (const float*)d_in[10];

    float* out_ls = (float*)d_out;                                   // [N,64] final -> log_softmax
    float* weight = (float*)d_out + (size_t)N_NODES * NCLASS;        // [N,9]

    char* ws = (char*)d_ws;
    size_t off = 0;
    auto alloc = [&](size_t bytes) {
        void* p = ws + off;
        off += (bytes + 255) & ~(size_t)255;
        return p;
    };
    float* ranked    = (float*)alloc((size_t)N_NODES * TOPK * 4);
    float* fA        = (float*)alloc((size_t)N_NODES * NCLASS * 4);
    float* fB        = (float*)alloc((size_t)N_NODES * NCLASS * 4);
    int*   counts    = (int*)alloc((size_t)N_NODES * 4);
    int*   partial   = (int*)alloc((size_t)N_NODES * 4);
    int*   row_start = (int*)alloc((size_t)(N_NODES + 1) * 4);
    int*   cursor    = (int*)alloc((size_t)N_NODES * 4);
    int*   blocksums = (int*)alloc(128 * 4);
    int2*  sedge     = (int2*)alloc((size_t)NEDGE * 8);

    const int SCAN_BLOCKS = (N_NODES + 1023) / 1024;  // 98

    // CSR build
    hipMemsetAsync(counts, 0, (size_t)N_NODES * 4, stream);
    hist_kernel<<<2048, 256, 0, stream>>>(arows, counts, NEDGE);
    scan_blocks<<<SCAN_BLOCKS, 1024, 0, stream>>>(counts, partial, blocksums, N_NODES);
    scan_sums<<<1, 64, 0, stream>>>(blocksums, SCAN_BLOCKS);
    finalize_rows<<<(N_NODES + 255) / 256, 256, 0, stream>>>(partial, blocksums, row_start, cursor,
                                                             N_NODES, NEDGE);
    scatter_edges<<<2048, 256, 0, stream>>>(arows, acols, avals, cursor, sedge, NEDGE);

    // gating MLP
    softmax_topk<<<(N_NODES + 3) / 4, 256, 0, stream>>>(g0, ranked, N_NODES);
    mlp_kernel<<<(N_NODES + TM - 1) / TM, 256, 0, stream>>>(ranked, W1, b1, W2, b2, W3, b3,
                                                            weight, N_NODES);

    // final = w0 * f ; then 8 chained spmm with fused accumulation
    init_final<<<(N_NODES * NCLASS + 255) / 256, 256, 0, stream>>>(f_pred, weight, out_ls, N_NODES);

    const float* xin = f_pred;
    float* bufs[2] = {fA, fB};
    for (int it = 0; it < DEGREE - 1; ++it) {
        float* y = bufs[it & 1];
        spmm_fused<<<(N_NODES + 3) / 4, 256, 0, stream>>>(row_start, sedge, xin, y, weight, out_ls,
                                                          it + 1, N_NODES);
        xin = y;
    }

    logsoftmax_inplace<<<(N_NODES + 3) / 4, 256, 0, stream>>>(out_ls, N_NODES);
}

// Round 3
// 1779.401 us; speedup vs baseline: 1.1785x; 1.1785x over previous
//
#include <hip/hip_runtime.h>
#include <hip/hip_bf16.h>

#define N_NODES 100000
#define NCLASS  64
#define NEDGE   1600000
#define NHID    256
#define TOPK    16
#define DEGREE  9

#define TM 16  // rows per block in MLP
#define H2PAD (NHID + 4)  // pad: bank = (4r+k)%32 spreads rows; rows stay 16B-aligned

__device__ __forceinline__ float fast_tanh(float x) {
    // tanh(x) = 1 - 2/(e^{2x}+1); saturates correctly at +/-inf
    float e = __expf(2.0f * x);
    return 1.0f - 2.0f / (e + 1.0f);
}

// ---------------- CSR build ----------------

__global__ void hist_kernel(const int* __restrict__ rows, int* __restrict__ counts, int e) {
    for (int i = blockIdx.x * blockDim.x + threadIdx.x; i < e; i += gridDim.x * blockDim.x)
        atomicAdd(&counts[rows[i]], 1);
}

__global__ __launch_bounds__(1024) void scan_blocks(const int* __restrict__ counts,
                                                    int* __restrict__ partial,
                                                    int* __restrict__ blocksums, int n) {
    __shared__ int s[1024];
    int tid = threadIdx.x;
    int gid = blockIdx.x * 1024 + tid;
    int v = (gid < n) ? counts[gid] : 0;
    s[tid] = v;
    __syncthreads();
    for (int off = 1; off < 1024; off <<= 1) {
        int t = (tid >= off) ? s[tid - off] : 0;
        __syncthreads();
        s[tid] += t;
        __syncthreads();
    }
    if (gid < n) partial[gid] = s[tid] - v;  // exclusive
    if (tid == 1023) blocksums[blockIdx.x] = s[1023];
}

__global__ void scan_sums(int* __restrict__ blocksums, int nb) {
    if (blockIdx.x == 0 && threadIdx.x == 0) {
        int run = 0;
        for (int i = 0; i < nb; ++i) { int v = blocksums[i]; blocksums[i] = run; run += v; }
    }
}

__global__ void finalize_rows(const int* __restrict__ partial, const int* __restrict__ blocksums,
                              int* __restrict__ row_start, int* __restrict__ cursor, int n, int e) {
    int i = blockIdx.x * blockDim.x + threadIdx.x;
    if (i < n) {
        int v = partial[i] + blocksums[i >> 10];
        row_start[i] = v;
        cursor[i] = v;
    }
    if (i == 0) row_start[n] = e;
}

__global__ void scatter_edges(const int* __restrict__ rows, const int* __restrict__ cols,
                              const float* __restrict__ vals, int* __restrict__ cursor,
                              int2* __restrict__ sedge, int e) {
    for (int i = blockIdx.x * blockDim.x + threadIdx.x; i < e; i += gridDim.x * blockDim.x) {
        int r = rows[i];
        int pos = atomicAdd(&cursor[r], 1);
        sedge[pos] = make_int2(cols[i], __float_as_int(vals[i]));
    }
}

// ---------------- softmax + top-16 (wave per row) ----------------

__global__ __launch_bounds__(256) void softmax_topk(const float* __restrict__ g0,
                                                    float* __restrict__ ranked, int n) {
    int wave = (blockIdx.x * 256 + threadIdx.x) >> 6;
    int lane = threadIdx.x & 63;
    if (wave >= n) return;
    float x = g0[(size_t)wave * NCLASS + lane];
    float m = x;
    #pragma unroll
    for (int o = 1; o < 64; o <<= 1) m = fmaxf(m, __shfl_xor(m, o));
    float p = expf(x - m);
    float s = p;
    #pragma unroll
    for (int o = 1; o < 64; o <<= 1) s += __shfl_xor(s, o);
    p /= s;
    // bitonic sort 64 lanes, descending (lane 0 = max)
    float v = p;
    #pragma unroll
    for (int k = 2; k <= 64; k <<= 1) {
        #pragma unroll
        for (int j = k >> 1; j > 0; j >>= 1) {
            float o = __shfl_xor(v, j);
            bool up = (lane & k) != 0;
            bool takeMax = (((lane & j) == 0) != up);
            v = takeMax ? fmaxf(v, o) : fminf(v, o);
        }
    }
    if (lane < TOPK) ranked[wave * TOPK + lane] = v;
}

// ---------------- MLP: [N,16] -> 512 -> 256 -> 9 ----------------
// Register-tiled: layer2 thread (tx,ty) owns 4 rows x 4 cols (16 acc);
// per 4-k step: 4 broadcast ds_read_b128 + 4 coalesced float4 W2 loads + 64 FMA.

__global__ __launch_bounds__(256) void mlp_kernel(const float* __restrict__ ranked,
                                                  const float* __restrict__ W1, const float* __restrict__ b1,
                                                  const float* __restrict__ W2, const float* __restrict__ b2,
                                                  const float* __restrict__ W3, const float* __restrict__ b3,
                                                  float* __restrict__ weight_out, int n) {
    __shared__ float s_rank[TM][TOPK];       // 1 KB
    __shared__ float s_h1[TM][2 * NHID];     // 32 KB
    __shared__ float s_h2[TM][H2PAD];        // 16.6 KB
    int t = threadIdx.x;
    int row0 = blockIdx.x * TM;

    // load ranked tile (TM*16 = 256 elements)
    {
        int r = t >> 4, k = t & 15;
        int gr = row0 + r;
        s_rank[r][k] = (gr < n) ? ranked[gr * TOPK + k] : 0.0f;
    }
    __syncthreads();

    // ---- layer 1: thread t owns h1 columns t and t+256, all 16 rows ----
    {
        float w1a[TOPK], w1b[TOPK];
        #pragma unroll
        for (int k = 0; k < TOPK; ++k) {
            w1a[k] = W1[k * (2 * NHID) + t];
            w1b[k] = W1[k * (2 * NHID) + t + NHID];
        }
        float ba = b1[t], bb = b1[t + NHID];
        #pragma unroll
        for (int r = 0; r < TM; ++r) {
            float4 q0 = *reinterpret_cast<const float4*>(&s_rank[r][0]);
            float4 q1 = *reinterpret_cast<const float4*>(&s_rank[r][4]);
            float4 q2 = *reinterpret_cast<const float4*>(&s_rank[r][8]);
            float4 q3 = *reinterpret_cast<const float4*>(&s_rank[r][12]);
            float rk[TOPK] = {q0.x, q0.y, q0.z, q0.w, q1.x, q1.y, q1.z, q1.w,
                              q2.x, q2.y, q2.z, q2.w, q3.x, q3.y, q3.z, q3.w};
            float a = ba, b = bb;
            #pragma unroll
            for (int k = 0; k < TOPK; ++k) {
                a = fmaf(rk[k], w1a[k], a);
                b = fmaf(rk[k], w1b[k], b);
            }
            s_h1[r][t] = fast_tanh(a);
            s_h1[r][t + NHID] = fast_tanh(b);
        }
    }
    __syncthreads();

    // ---- layer 2: 4x4 register tile per thread ----
    {
        int tx = t & 63;   // cols 4*tx .. 4*tx+3
        int ty = t >> 6;   // rows 4*ty .. 4*ty+3
        float4 b2v = *reinterpret_cast<const float4*>(&b2[tx * 4]);
        float acc[4][4];
        #pragma unroll
        for (int rr = 0; rr < 4; ++rr) {
            acc[rr][0] = b2v.x; acc[rr][1] = b2v.y; acc[rr][2] = b2v.z; acc[rr][3] = b2v.w;
        }
        const float* w2p = W2 + tx * 4;
        for (int k = 0; k < 2 * NHID; k += 4) {
            float4 h[4];
            #pragma unroll
            for (int rr = 0; rr < 4; ++rr)
                h[rr] = *reinterpret_cast<const float4*>(&s_h1[ty * 4 + rr][k]);
            #pragma unroll
            for (int kk = 0; kk < 4; ++kk) {
                float4 w = *reinterpret_cast<const float4*>(&w2p[(size_t)(k + kk) * NHID]);
                #pragma unroll
                for (int rr = 0; rr < 4; ++rr) {
                    float hv = (kk == 0) ? h[rr].x : (kk == 1) ? h[rr].y : (kk == 2) ? h[rr].z : h[rr].w;
                    acc[rr][0] = fmaf(hv, w.x, acc[rr][0]);
                    acc[rr][1] = fmaf(hv, w.y, acc[rr][1]);
                    acc[rr][2] = fmaf(hv, w.z, acc[rr][2]);
                    acc[rr][3] = fmaf(hv, w.w, acc[rr][3]);
                }
            }
        }
        #pragma unroll
        for (int rr = 0; rr < 4; ++rr) {
            #pragma unroll
            for (int cc = 0; cc < 4; ++cc)
                s_h2[ty * 4 + rr][tx * 4 + cc] = fast_tanh(acc[rr][cc]);
        }
    }
    __syncthreads();

    // ---- layer 3: TM x 9 = 144 outputs, float4 k-unroll ----
    if (t < TM * DEGREE) {
        int r = t / DEGREE, d = t % DEGREE;
        float acc = b3[d];
        for (int k = 0; k < NHID; k += 4) {
            float4 h = *reinterpret_cast<const float4*>(&s_h2[r][k]);
            acc = fmaf(h.x, W3[(k + 0) * DEGREE + d], acc);
            acc = fmaf(h.y, W3[(k + 1) * DEGREE + d], acc);
            acc = fmaf(h.z, W3[(k + 2) * DEGREE + d], acc);
            acc = fmaf(h.w, W3[(k + 3) * DEGREE + d], acc);
        }
        int gr = row0 + r;
        if (gr < n) weight_out[gr * DEGREE + d] = acc;
    }
}

// ---------------- final init + SpMM chain ----------------

__global__ void init_final(const float* __restrict__ fpred, const float* __restrict__ weight,
                           float* __restrict__ finalbuf, int n) {
    int i = blockIdx.x * blockDim.x + threadIdx.x;
    if (i < n * NCLASS) {
        int row = i >> 6;
        finalbuf[i] = weight[row * DEGREE] * fpred[i];
    }
}

__global__ __launch_bounds__(256) void spmm_fused(const int* __restrict__ row_start,
                                                  const int2* __restrict__ sedge,
                                                  const float* __restrict__ x,
                                                  float* __restrict__ y,
                                                  const float* __restrict__ weight,
                                                  float* __restrict__ finalbuf,
                                                  int wcol, int n) {
    int wave = (blockIdx.x * 256 + threadIdx.x) >> 6;
    int lane = threadIdx.x & 63;
    if (wave >= n) return;
    int e0 = row_start[wave], e1 = row_start[wave + 1];
    float acc = 0.0f;
    int2 ef = (e0 < e1) ? sedge[e0] : make_int2(0, 0);
    for (int e = e0; e < e1; ++e) {
        int2 cur = ef;
        if (e + 1 < e1) ef = sedge[e + 1];           // prefetch next edge
        acc += __int_as_float(cur.y) * x[cur.x * NCLASS + lane];
    }
    int o = wave * NCLASS + lane;
    y[o] = acc;
    finalbuf[o] += weight[wave * DEGREE + wcol] * acc;
}

__global__ __launch_bounds__(256) void logsoftmax_inplace(float* __restrict__ out, int n) {
    int wave = (blockIdx.x * 256 + threadIdx.x) >> 6;
    int lane = threadIdx.x & 63;
    if (wave >= n) return;
    int o = wave * NCLASS + lane;
    float x = out[o];
    float m = x;
    #pragma unroll
    for (int off = 1; off < 64; off <<= 1) m = fmaxf(m, __shfl_xor(m, off));
    float p = expf(x - m);
    float s = p;
    #pragma unroll
    for (int off = 1; off < 64; off <<= 1) s += __shfl_xor(s, off);
    out[o] = x - m - logf(s);
}

// ---------------- launch ----------------

extern "C" void kernel_launch(void* const* d_in, const int* in_sizes, int n_in,
                              void* d_out, int out_size, void* d_ws, size_t ws_size,
                              hipStream_t stream) {
    const float* f_pred = (const float*)d_in[0];
    const float* g0     = (const float*)d_in[1];
    const int*   arows  = (const int*)d_in[2];
    const int*   acols  = (const int*)d_in[3];
    const float* avals  = (const float*)d_in[4];
    const float* W1     = (const float*)d_in[5];
    const float* b1     = (const float*)d_in[6];
    const float* W2     = (const float*)d_in[7];
    const float* b2     = (const float*)d_in[8];
    const float* W3     = (const float*)d_in[9];
    const float* b3     = (const float*)d_in[10];

    float* out_ls = (float*)d_out;                                   // [N,64] final -> log_softmax
    float* weight = (float*)d_out + (size_t)N_NODES * NCLASS;        // [N,9]

    char* ws = (char*)d_ws;
    size_t off = 0;
    auto alloc = [&](size_t bytes) {
        void* p = ws + off;
        off += (bytes + 255) & ~(size_t)255;
        return p;
    };
    float* ranked    = (float*)alloc((size_t)N_NODES * TOPK * 4);
    float* fA        = (float*)alloc((size_t)N_NODES * NCLASS * 4);
    float* fB        = (float*)alloc((size_t)N_NODES * NCLASS * 4);
    int*   counts    = (int*)alloc((size_t)N_NODES * 4);
    int*   partial   = (int*)alloc((size_t)N_NODES * 4);
    int*   row_start = (int*)alloc((size_t)(N_NODES + 1) * 4);
    int*   cursor    = (int*)alloc((size_t)N_NODES * 4);
    int*   blocksums = (int*)alloc(128 * 4);
    int2*  sedge     = (int2*)alloc((size_t)NEDGE * 8);

    const int SCAN_BLOCKS = (N_NODES + 1023) / 1024;  // 98

    // CSR build
    hipMemsetAsync(counts, 0, (size_t)N_NODES * 4, stream);
    hist_kernel<<<2048, 256, 0, stream>>>(arows, counts, NEDGE);
    scan_blocks<<<SCAN_BLOCKS, 1024, 0, stream>>>(counts, partial, blocksums, N_NODES);
    scan_sums<<<1, 64, 0, stream>>>(blocksums, SCAN_BLOCKS);
    finalize_rows<<<(N_NODES + 255) / 256, 256, 0, stream>>>(partial, blocksums, row_start, cursor,
                                                             N_NODES, NEDGE);
    scatter_edges<<<2048, 256, 0, stream>>>(arows, acols, avals, cursor, sedge, NEDGE);

    // gating MLP
    softmax_topk<<<(N_NODES + 3) / 4, 256, 0, stream>>>(g0, ranked, N_NODES);
    mlp_kernel<<<(N_NODES + TM - 1) / TM, 256, 0, stream>>>(ranked, W1, b1, W2, b2, W3, b3,
                                                            weight, N_NODES);

    // final = w0 * f ; then 8 chained spmm with fused accumulation
    init_final<<<(N_NODES * NCLASS + 255) / 256, 256, 0, stream>>>(f_pred, weight, out_ls, N_NODES);

    const float* xin = f_pred;
    float* bufs[2] = {fA, fB};
    for (int it = 0; it < DEGREE - 1; ++it) {
        float* y = bufs[it & 1];
        spmm_fused<<<(N_NODES + 3) / 4, 256, 0, stream>>>(row_start, sedge, xin, y, weight, out_ls,
                                                          it + 1, N_NODES);
        xin = y;
    }

    logsoftmax_inplace<<<(N_NODES + 3) / 4, 256, 0, stream>>>(out_ls, N_NODES);
}

// Round 4
// 1515.703 us; speedup vs baseline: 1.3836x; 1.1740x over previous
//
#include <hip/hip_runtime.h>
#include <hip/hip_bf16.h>

#define N_NODES 100000
#define NCLASS  64
#define NEDGE   1600000
#define NHID    256
#define TOPK    16
#define DEGREE  9

#define TM 16            // rows per block in MLP
#define KCHUNK 128       // k-values per LDS chunk in MLP (4 chunks of 512)
#define H2PAD (NHID + 4) // pad: bank = (4r+k)%32 spreads rows; rows stay 16B-aligned

__device__ __forceinline__ float fast_tanh(float x) {
    // tanh(x) = 1 - 2/(e^{2x}+1); saturates correctly at +/-inf
    float e = __expf(2.0f * x);
    return 1.0f - 2.0f / (e + 1.0f);
}

// ---------------- CSR build ----------------

__global__ void hist_kernel(const int* __restrict__ rows, int* __restrict__ counts, int e) {
    for (int i = blockIdx.x * blockDim.x + threadIdx.x; i < e; i += gridDim.x * blockDim.x)
        atomicAdd(&counts[rows[i]], 1);
}

__global__ __launch_bounds__(1024) void scan_blocks(const int* __restrict__ counts,
                                                    int* __restrict__ partial,
                                                    int* __restrict__ blocksums, int n) {
    __shared__ int s[1024];
    int tid = threadIdx.x;
    int gid = blockIdx.x * 1024 + tid;
    int v = (gid < n) ? counts[gid] : 0;
    s[tid] = v;
    __syncthreads();
    for (int off = 1; off < 1024; off <<= 1) {
        int t = (tid >= off) ? s[tid - off] : 0;
        __syncthreads();
        s[tid] += t;
        __syncthreads();
    }
    if (gid < n) partial[gid] = s[tid] - v;  // exclusive
    if (tid == 1023) blocksums[blockIdx.x] = s[1023];
}

__global__ void scan_sums(int* __restrict__ blocksums, int nb) {
    if (blockIdx.x == 0 && threadIdx.x == 0) {
        int run = 0;
        for (int i = 0; i < nb; ++i) { int v = blocksums[i]; blocksums[i] = run; run += v; }
    }
}

__global__ void finalize_rows(const int* __restrict__ partial, const int* __restrict__ blocksums,
                              int* __restrict__ row_start, int* __restrict__ cursor, int n, int e) {
    int i = blockIdx.x * blockDim.x + threadIdx.x;
    if (i < n) {
        int v = partial[i] + blocksums[i >> 10];
        row_start[i] = v;
        cursor[i] = v;
    }
    if (i == 0) row_start[n] = e;
}

__global__ void scatter_edges(const int* __restrict__ rows, const int* __restrict__ cols,
                              const float* __restrict__ vals, int* __restrict__ cursor,
                              int2* __restrict__ sedge, int e) {
    for (int i = blockIdx.x * blockDim.x + threadIdx.x; i < e; i += gridDim.x * blockDim.x) {
        int r = rows[i];
        int pos = atomicAdd(&cursor[r], 1);
        sedge[pos] = make_int2(cols[i], __float_as_int(vals[i]));
    }
}

// ---------------- softmax + top-16 (wave per row) ----------------

__global__ __launch_bounds__(256) void softmax_topk(const float* __restrict__ g0,
                                                    float* __restrict__ ranked, int n) {
    int wave = (blockIdx.x * 256 + threadIdx.x) >> 6;
    int lane = threadIdx.x & 63;
    if (wave >= n) return;
    float x = g0[(size_t)wave * NCLASS + lane];
    float m = x;
    #pragma unroll
    for (int o = 1; o < 64; o <<= 1) m = fmaxf(m, __shfl_xor(m, o));
    float p = expf(x - m);
    float s = p;
    #pragma unroll
    for (int o = 1; o < 64; o <<= 1) s += __shfl_xor(s, o);
    p /= s;
    // bitonic sort 64 lanes, descending (lane 0 = max)
    float v = p;
    #pragma unroll
    for (int k = 2; k <= 64; k <<= 1) {
        #pragma unroll
        for (int j = k >> 1; j > 0; j >>= 1) {
            float o = __shfl_xor(v, j);
            bool up = (lane & k) != 0;
            bool takeMax = (((lane & j) == 0) != up);
            v = takeMax ? fmaxf(v, o) : fminf(v, o);
        }
    }
    if (lane < TOPK) ranked[wave * TOPK + lane] = v;
}

// ---------------- MLP: [N,16] -> 512 -> 256 -> 9 ----------------
// k-chunked: h1 computed/consumed in 4 chunks of 128 via an 8KB LDS buffer.
// LDS ~26KB -> 6 blocks/CU (24 waves/CU) so L2-latency of W2 loads is hidden.
// Layer2: 4x4 register tile/thread: 4 ds_read_b128 + 4 float4 W2 loads per 64 FMA.

__global__ __launch_bounds__(256) void mlp_kernel(const float* __restrict__ ranked,
                                                  const float* __restrict__ W1, const float* __restrict__ b1,
                                                  const float* __restrict__ W2, const float* __restrict__ b2,
                                                  const float* __restrict__ W3, const float* __restrict__ b3,
                                                  float* __restrict__ weight_out, int n) {
    __shared__ float s_rank[TM][TOPK];       // 1 KB
    __shared__ float s_h1[TM][KCHUNK];       // 8 KB
    __shared__ float s_h2[TM][H2PAD];        // 16.6 KB
    int t = threadIdx.x;
    int row0 = blockIdx.x * TM;

    // load ranked tile (TM*16 = 256 elements)
    {
        int r = t >> 4, k = t & 15;
        int gr = row0 + r;
        s_rank[r][k] = (gr < n) ? ranked[gr * TOPK + k] : 0.0f;
    }

    // layer-2 state (persists across chunks)
    const int tx = t & 63;   // cols 4*tx .. 4*tx+3
    const int ty = t >> 6;   // rows 4*ty .. 4*ty+3
    float acc[4][4];
    {
        float4 b2v = *reinterpret_cast<const float4*>(&b2[tx * 4]);
        #pragma unroll
        for (int rr = 0; rr < 4; ++rr) {
            acc[rr][0] = b2v.x; acc[rr][1] = b2v.y; acc[rr][2] = b2v.z; acc[rr][3] = b2v.w;
        }
    }
    const float* w2p = W2 + tx * 4;

    // layer-1 thread mapping: column j within chunk, 8-row half
    const int j  = t & (KCHUNK - 1);
    const int rh = (t >> 7) * 8;

    __syncthreads();

    for (int c = 0; c < 2 * NHID / KCHUNK; ++c) {
        const int kbase = c * KCHUNK;
        // ---- layer 1 (chunk): compute h1 cols [kbase, kbase+KCHUNK) for 8 rows ----
        {
            const int col = kbase + j;
            float w1c[TOPK];
            #pragma unroll
            for (int k = 0; k < TOPK; ++k) w1c[k] = W1[k * (2 * NHID) + col];
            float bb = b1[col];
            #pragma unroll
            for (int r = rh; r < rh + 8; ++r) {
                float4 q0 = *reinterpret_cast<const float4*>(&s_rank[r][0]);
                float4 q1 = *reinterpret_cast<const float4*>(&s_rank[r][4]);
                float4 q2 = *reinterpret_cast<const float4*>(&s_rank[r][8]);
                float4 q3 = *reinterpret_cast<const float4*>(&s_rank[r][12]);
                float rk[TOPK] = {q0.x, q0.y, q0.z, q0.w, q1.x, q1.y, q1.z, q1.w,
                                  q2.x, q2.y, q2.z, q2.w, q3.x, q3.y, q3.z, q3.w};
                float a = bb;
                #pragma unroll
                for (int k = 0; k < TOPK; ++k) a = fmaf(rk[k], w1c[k], a);
                s_h1[r][j] = fast_tanh(a);
            }
        }
        __syncthreads();

        // ---- layer 2 (chunk): accumulate 4x4 tile over KCHUNK k-values ----
        for (int kk = 0; kk < KCHUNK; kk += 4) {
            float4 h[4];
            #pragma unroll
            for (int rr = 0; rr < 4; ++rr)
                h[rr] = *reinterpret_cast<const float4*>(&s_h1[ty * 4 + rr][kk]);
            #pragma unroll
            for (int kk2 = 0; kk2 < 4; ++kk2) {
                float4 w = *reinterpret_cast<const float4*>(&w2p[(size_t)(kbase + kk + kk2) * NHID]);
                #pragma unroll
                for (int rr = 0; rr < 4; ++rr) {
                    float hv = (kk2 == 0) ? h[rr].x : (kk2 == 1) ? h[rr].y : (kk2 == 2) ? h[rr].z : h[rr].w;
                    acc[rr][0] = fmaf(hv, w.x, acc[rr][0]);
                    acc[rr][1] = fmaf(hv, w.y, acc[rr][1]);
                    acc[rr][2] = fmaf(hv, w.z, acc[rr][2]);
                    acc[rr][3] = fmaf(hv, w.w, acc[rr][3]);
                }
            }
        }
        __syncthreads();
    }

    // write h2
    #pragma unroll
    for (int rr = 0; rr < 4; ++rr) {
        #pragma unroll
        for (int cc = 0; cc < 4; ++cc)
            s_h2[ty * 4 + rr][tx * 4 + cc] = fast_tanh(acc[rr][cc]);
    }
    __syncthreads();

    // ---- layer 3: TM x 9 = 144 outputs, float4 k-unroll ----
    if (t < TM * DEGREE) {
        int r = t / DEGREE, d = t % DEGREE;
        float a3 = b3[d];
        for (int k = 0; k < NHID; k += 4) {
            float4 h = *reinterpret_cast<const float4*>(&s_h2[r][k]);
            a3 = fmaf(h.x, W3[(k + 0) * DEGREE + d], a3);
            a3 = fmaf(h.y, W3[(k + 1) * DEGREE + d], a3);
            a3 = fmaf(h.z, W3[(k + 2) * DEGREE + d], a3);
            a3 = fmaf(h.w, W3[(k + 3) * DEGREE + d], a3);
        }
        int gr = row0 + r;
        if (gr < n) weight_out[gr * DEGREE + d] = a3;
    }
}

// ---------------- final init + SpMM chain ----------------

__global__ void init_final(const float* __restrict__ fpred, const float* __restrict__ weight,
                           float* __restrict__ finalbuf, int n) {
    int i = blockIdx.x * blockDim.x + threadIdx.x;
    if (i < n * NCLASS) {
        int row = i >> 6;
        finalbuf[i] = weight[row * DEGREE] * fpred[i];
    }
}

// wave per row, lane = feature; 4-way ILP on the gather chain
__global__ __launch_bounds__(256) void spmm_fused(const int* __restrict__ row_start,
                                                  const int2* __restrict__ sedge,
                                                  const float* __restrict__ x,
                                                  float* __restrict__ y,
                                                  const float* __restrict__ weight,
                                                  float* __restrict__ finalbuf,
                                                  int wcol, int n) {
    int wave = (blockIdx.x * 256 + threadIdx.x) >> 6;
    int lane = threadIdx.x & 63;
    if (wave >= n) return;
    int e0 = row_start[wave], e1 = row_start[wave + 1];
    float a0 = 0.0f, a1 = 0.0f, a2 = 0.0f, a3 = 0.0f;
    int e = e0;
    for (; e + 3 < e1; e += 4) {
        int2 d0 = sedge[e];
        int2 d1 = sedge[e + 1];
        int2 d2 = sedge[e + 2];
        int2 d3 = sedge[e + 3];
        float x0 = x[(size_t)d0.x * NCLASS + lane];
        float x1 = x[(size_t)d1.x * NCLASS + lane];
        float x2 = x[(size_t)d2.x * NCLASS + lane];
        float x3 = x[(size_t)d3.x * NCLASS + lane];
        a0 = fmaf(__int_as_float(d0.y), x0, a0);
        a1 = fmaf(__int_as_float(d1.y), x1, a1);
        a2 = fmaf(__int_as_float(d2.y), x2, a2);
        a3 = fmaf(__int_as_float(d3.y), x3, a3);
    }
    for (; e < e1; ++e) {
        int2 d = sedge[e];
        a0 = fmaf(__int_as_float(d.y), x[(size_t)d.x * NCLASS + lane], a0);
    }
    float acc = (a0 + a1) + (a2 + a3);
    int o = wave * NCLASS + lane;
    y[o] = acc;
    finalbuf[o] += weight[wave * DEGREE + wcol] * acc;
}

__global__ __launch_bounds__(256) void logsoftmax_inplace(float* __restrict__ out, int n) {
    int wave = (blockIdx.x * 256 + threadIdx.x) >> 6;
    int lane = threadIdx.x & 63;
    if (wave >= n) return;
    int o = wave * NCLASS + lane;
    float x = out[o];
    float m = x;
    #pragma unroll
    for (int off = 1; off < 64; off <<= 1) m = fmaxf(m, __shfl_xor(m, off));
    float p = expf(x - m);
    float s = p;
    #pragma unroll
    for (int off = 1; off < 64; off <<= 1) s += __shfl_xor(s, off);
    out[o] = x - m - logf(s);
}

// ---------------- launch ----------------

extern "C" void kernel_launch(void* const* d_in, const int* in_sizes, int n_in,
                              void* d_out, int out_size, void* d_ws, size_t ws_size,
                              hipStream_t stream) {
    const float* f_pred = (const float*)d_in[0];
    const float* g0     = (const float*)d_in[1];
    const int*   arows  = (const int*)d_in[2];
    const int*   acols  = (const int*)d_in[3];
    const float* avals  = (const float*)d_in[4];
    const float* W1     = (const float*)d_in[5];
    const float* b1     = (const float*)d_in[6];
    const float* W2     = (const float*)d_in[7];
    const float* b2     = (const float*)d_in[8];
    const float* W3     = (const float*)d_in[9];
    const float* b3     = (const float*)d_in[10];

    float* out_ls = (float*)d_out;                                   // [N,64] final -> log_softmax
    float* weight = (float*)d_out + (size_t)N_NODES * NCLASS;        // [N,9]

    char* ws = (char*)d_ws;
    size_t off = 0;
    auto alloc = [&](size_t bytes) {
        void* p = ws + off;
        off += (bytes + 255) & ~(size_t)255;
        return p;
    };
    float* ranked    = (float*)alloc((size_t)N_NODES * TOPK * 4);
    float* fA        = (float*)alloc((size_t)N_NODES * NCLASS * 4);
    float* fB        = (float*)alloc((size_t)N_NODES * NCLASS * 4);
    int*   counts    = (int*)alloc((size_t)N_NODES * 4);
    int*   partial   = (int*)alloc((size_t)N_NODES * 4);
    int*   row_start = (int*)alloc((size_t)(N_NODES + 1) * 4);
    int*   cursor    = (int*)alloc((size_t)N_NODES * 4);
    int*   blocksums = (int*)alloc(128 * 4);
    int2*  sedge     = (int2*)alloc((size_t)NEDGE * 8);

    const int SCAN_BLOCKS = (N_NODES + 1023) / 1024;  // 98

    // CSR build
    hipMemsetAsync(counts, 0, (size_t)N_NODES * 4, stream);
    hist_kernel<<<2048, 256, 0, stream>>>(arows, counts, NEDGE);
    scan_blocks<<<SCAN_BLOCKS, 1024, 0, stream>>>(counts, partial, blocksums, N_NODES);
    scan_sums<<<1, 64, 0, stream>>>(blocksums, SCAN_BLOCKS);
    finalize_rows<<<(N_NODES + 255) / 256, 256, 0, stream>>>(partial, blocksums, row_start, cursor,
                                                             N_NODES, NEDGE);
    scatter_edges<<<2048, 256, 0, stream>>>(arows, acols, avals, cursor, sedge, NEDGE);

    // gating MLP
    softmax_topk<<<(N_NODES + 3) / 4, 256, 0, stream>>>(g0, ranked, N_NODES);
    mlp_kernel<<<(N_NODES + TM - 1) / TM, 256, 0, stream>>>(ranked, W1, b1, W2, b2, W3, b3,
                                                            weight, N_NODES);

    // final = w0 * f ; then 8 chained spmm with fused accumulation
    init_final<<<(N_NODES * NCLASS + 255) / 256, 256, 0, stream>>>(f_pred, weight, out_ls, N_NODES);

    const float* xin = f_pred;
    float* bufs[2] = {fA, fB};
    for (int it = 0; it < DEGREE - 1; ++it) {
        float* y = bufs[it & 1];
        spmm_fused<<<(N_NODES + 3) / 4, 256, 0, stream>>>(row_start, sedge, xin, y, weight, out_ls,
                                                          it + 1, N_NODES);
        xin = y;
    }

    logsoftmax_inplace<<<(N_NODES + 3) / 4, 256, 0, stream>>>(out_ls, N_NODES);
}

// Round 5
// 1376.843 us; speedup vs baseline: 1.5231x; 1.1009x over previous
//
#include <hip/hip_runtime.h>
#include <hip/hip_bf16.h>

#define N_NODES 100000
#define NCLASS  64
#define NEDGE   1600000
#define NHID    256
#define TOPK    16
#define DEGREE  9

#define TM 32            // rows per block in MLP
#define KCHUNK 128       // k-values per LDS chunk in MLP (4 chunks of 512)
#define H2PAD (NHID + 4) // pad: bank = (4r+k)%32 spreads rows; rows stay 16B-aligned

__device__ __forceinline__ float fast_tanh(float x) {
    // tanh(x) = 1 - 2/(e^{2x}+1); saturates correctly at +/-inf
    float e = __expf(2.0f * x);
    return 1.0f - 2.0f / (e + 1.0f);
}

// ---------------- CSR build ----------------

__global__ void hist_kernel(const int* __restrict__ rows, int* __restrict__ counts, int e) {
    for (int i = blockIdx.x * blockDim.x + threadIdx.x; i < e; i += gridDim.x * blockDim.x)
        atomicAdd(&counts[rows[i]], 1);
}

__global__ __launch_bounds__(1024) void scan_blocks(const int* __restrict__ counts,
                                                    int* __restrict__ partial,
                                                    int* __restrict__ blocksums, int n) {
    __shared__ int s[1024];
    int tid = threadIdx.x;
    int gid = blockIdx.x * 1024 + tid;
    int v = (gid < n) ? counts[gid] : 0;
    s[tid] = v;
    __syncthreads();
    for (int off = 1; off < 1024; off <<= 1) {
        int t = (tid >= off) ? s[tid - off] : 0;
        __syncthreads();
        s[tid] += t;
        __syncthreads();
    }
    if (gid < n) partial[gid] = s[tid] - v;  // exclusive
    if (tid == 1023) blocksums[blockIdx.x] = s[1023];
}

__global__ void scan_sums(int* __restrict__ blocksums, int nb) {
    if (blockIdx.x == 0 && threadIdx.x == 0) {
        int run = 0;
        for (int i = 0; i < nb; ++i) { int v = blocksums[i]; blocksums[i] = run; run += v; }
    }
}

__global__ void finalize_rows(const int* __restrict__ partial, const int* __restrict__ blocksums,
                              int* __restrict__ row_start, int* __restrict__ cursor, int n, int e) {
    int i = blockIdx.x * blockDim.x + threadIdx.x;
    if (i < n) {
        int v = partial[i] + blocksums[i >> 10];
        row_start[i] = v;
        cursor[i] = v;
    }
    if (i == 0) row_start[n] = e;
}

__global__ void scatter_edges(const int* __restrict__ rows, const int* __restrict__ cols,
                              const float* __restrict__ vals, int* __restrict__ cursor,
                              int2* __restrict__ sedge, int e) {
    for (int i = blockIdx.x * blockDim.x + threadIdx.x; i < e; i += gridDim.x * blockDim.x) {
        int r = rows[i];
        int pos = atomicAdd(&cursor[r], 1);
        sedge[pos] = make_int2(cols[i], __float_as_int(vals[i]));
    }
}

// ---------------- softmax + top-16 (wave per row) ----------------

__global__ __launch_bounds__(256) void softmax_topk(const float* __restrict__ g0,
                                                    float* __restrict__ ranked, int n) {
    int wave = (blockIdx.x * 256 + threadIdx.x) >> 6;
    int lane = threadIdx.x & 63;
    if (wave >= n) return;
    float x = g0[(size_t)wave * NCLASS + lane];
    float m = x;
    #pragma unroll
    for (int o = 1; o < 64; o <<= 1) m = fmaxf(m, __shfl_xor(m, o));
    float p = expf(x - m);
    float s = p;
    #pragma unroll
    for (int o = 1; o < 64; o <<= 1) s += __shfl_xor(s, o);
    p /= s;
    // bitonic sort 64 lanes, descending (lane 0 = max)
    float v = p;
    #pragma unroll
    for (int k = 2; k <= 64; k <<= 1) {
        #pragma unroll
        for (int j = k >> 1; j > 0; j >>= 1) {
            float o = __shfl_xor(v, j);
            bool up = (lane & k) != 0;
            bool takeMax = (((lane & j) == 0) != up);
            v = takeMax ? fmaxf(v, o) : fminf(v, o);
        }
    }
    if (lane < TOPK) ranked[wave * TOPK + lane] = v;
}

// ---------------- MLP: [N,16] -> 512 -> 256 -> 9 ----------------
// TM=32, 8 rows x 4 cols per thread: per 4-k step 4 float4 W2 loads (64B)
// feed 128 FMA -> 4 FLOP per L1 byte (was 1). W2 loads pipelined 1 step.
// h1 reads are wave-uniform LDS broadcasts (free). L1 traffic/CU halves.

__global__ __launch_bounds__(256) void mlp_kernel(const float* __restrict__ ranked,
                                                  const float* __restrict__ W1, const float* __restrict__ b1,
                                                  const float* __restrict__ W2, const float* __restrict__ b2,
                                                  const float* __restrict__ W3, const float* __restrict__ b3,
                                                  float* __restrict__ weight_out, int n) {
    __shared__ float s_rank[TM][TOPK];       // 2 KB
    __shared__ float s_h1[TM][KCHUNK];       // 16 KB
    __shared__ float s_h2[TM][H2PAD];        // 33.3 KB
    int t = threadIdx.x;
    int row0 = blockIdx.x * TM;

    // load ranked tile (TM*16 = 512 elements, 2 per thread)
    for (int idx = t; idx < TM * TOPK; idx += 256) {
        int r = idx >> 4, k = idx & 15;
        int gr = row0 + r;
        s_rank[r][k] = (gr < n) ? ranked[gr * TOPK + k] : 0.0f;
    }

    // layer-2 state (persists across chunks): 8 rows x 4 cols per thread
    const int tx = t & 63;   // cols 4*tx .. 4*tx+3
    const int ty = t >> 6;   // rows 8*ty .. 8*ty+7
    float acc[8][4];
    {
        float4 b2v = *reinterpret_cast<const float4*>(&b2[tx * 4]);
        #pragma unroll
        for (int rr = 0; rr < 8; ++rr) {
            acc[rr][0] = b2v.x; acc[rr][1] = b2v.y; acc[rr][2] = b2v.z; acc[rr][3] = b2v.w;
        }
    }

    // layer-1 thread mapping: column j within chunk, 16-row half
    const int j  = t & (KCHUNK - 1);
    const int rh = (t >> 7) * (TM / 2);

    __syncthreads();

    for (int c = 0; c < 2 * NHID / KCHUNK; ++c) {
        const int kbase = c * KCHUNK;
        // ---- layer 1 (chunk): compute h1 cols [kbase, kbase+KCHUNK) for 16 rows ----
        {
            const int col = kbase + j;
            float w1c[TOPK];
            #pragma unroll
            for (int k = 0; k < TOPK; ++k) w1c[k] = W1[k * (2 * NHID) + col];
            float bb = b1[col];
            #pragma unroll 4
            for (int r = rh; r < rh + TM / 2; ++r) {
                float4 q0 = *reinterpret_cast<const float4*>(&s_rank[r][0]);
                float4 q1 = *reinterpret_cast<const float4*>(&s_rank[r][4]);
                float4 q2 = *reinterpret_cast<const float4*>(&s_rank[r][8]);
                float4 q3 = *reinterpret_cast<const float4*>(&s_rank[r][12]);
                float rk[TOPK] = {q0.x, q0.y, q0.z, q0.w, q1.x, q1.y, q1.z, q1.w,
                                  q2.x, q2.y, q2.z, q2.w, q3.x, q3.y, q3.z, q3.w};
                float a = bb;
                #pragma unroll
                for (int k = 0; k < TOPK; ++k) a = fmaf(rk[k], w1c[k], a);
                s_h1[r][j] = fast_tanh(a);
            }
        }
        __syncthreads();

        // ---- layer 2 (chunk): 8x4 tile over KCHUNK k-values, W2 pipelined ----
        {
            const float* wk = W2 + (size_t)kbase * NHID + (tx << 2);
            float4 wa0 = *reinterpret_cast<const float4*>(wk);
            float4 wa1 = *reinterpret_cast<const float4*>(wk + NHID);
            float4 wa2 = *reinterpret_cast<const float4*>(wk + 2 * NHID);
            float4 wa3 = *reinterpret_cast<const float4*>(wk + 3 * NHID);
            wk += 4 * NHID;
            for (int kk = 0; kk < KCHUNK; kk += 4) {
                float4 w0 = wa0, w1 = wa1, w2v = wa2, w3v = wa3;
                if (kk + 4 < KCHUNK) {
                    wa0 = *reinterpret_cast<const float4*>(wk);
                    wa1 = *reinterpret_cast<const float4*>(wk + NHID);
                    wa2 = *reinterpret_cast<const float4*>(wk + 2 * NHID);
                    wa3 = *reinterpret_cast<const float4*>(wk + 3 * NHID);
                    wk += 4 * NHID;
                }
                float4 h[8];
                #pragma unroll
                for (int rr = 0; rr < 8; ++rr)
                    h[rr] = *reinterpret_cast<const float4*>(&s_h1[ty * 8 + rr][kk]);
                #pragma unroll
                for (int kk2 = 0; kk2 < 4; ++kk2) {
                    float4 w = (kk2 == 0) ? w0 : (kk2 == 1) ? w1 : (kk2 == 2) ? w2v : w3v;
                    #pragma unroll
                    for (int rr = 0; rr < 8; ++rr) {
                        float hv = (kk2 == 0) ? h[rr].x : (kk2 == 1) ? h[rr].y
                                 : (kk2 == 2) ? h[rr].z : h[rr].w;
                        acc[rr][0] = fmaf(hv, w.x, acc[rr][0]);
                        acc[rr][1] = fmaf(hv, w.y, acc[rr][1]);
                        acc[rr][2] = fmaf(hv, w.z, acc[rr][2]);
                        acc[rr][3] = fmaf(hv, w.w, acc[rr][3]);
                    }
                }
            }
        }
        __syncthreads();
    }

    // write h2
    #pragma unroll
    for (int rr = 0; rr < 8; ++rr) {
        #pragma unroll
        for (int cc = 0; cc < 4; ++cc)
            s_h2[ty * 8 + rr][tx * 4 + cc] = fast_tanh(acc[rr][cc]);
    }
    __syncthreads();

    // ---- layer 3: TM x 9 = 288 outputs, float4 k-unroll ----
    for (int idx = t; idx < TM * DEGREE; idx += 256) {
        int r = idx / DEGREE, d = idx % DEGREE;
        float a3 = b3[d];
        for (int k = 0; k < NHID; k += 4) {
            float4 h = *reinterpret_cast<const float4*>(&s_h2[r][k]);
            a3 = fmaf(h.x, W3[(k + 0) * DEGREE + d], a3);
            a3 = fmaf(h.y, W3[(k + 1) * DEGREE + d], a3);
            a3 = fmaf(h.z, W3[(k + 2) * DEGREE + d], a3);
            a3 = fmaf(h.w, W3[(k + 3) * DEGREE + d], a3);
        }
        int gr = row0 + r;
        if (gr < n) weight_out[gr * DEGREE + d] = a3;
    }
}

// ---------------- final init + SpMM chain ----------------

__global__ void init_final(const float* __restrict__ fpred, const float* __restrict__ weight,
                           float* __restrict__ finalbuf, int n) {
    int i = blockIdx.x * blockDim.x + threadIdx.x;
    if (i < n * NCLASS) {
        int row = i >> 6;
        finalbuf[i] = weight[row * DEGREE] * fpred[i];
    }
}

// wave per row, lane = feature; 8-way ILP on the gather chain
__global__ __launch_bounds__(256) void spmm_fused(const int* __restrict__ row_start,
                                                  const int2* __restrict__ sedge,
                                                  const float* __restrict__ x,
                                                  float* __restrict__ y,
                                                  const float* __restrict__ weight,
                                                  float* __restrict__ finalbuf,
                                                  int wcol, int n) {
    int wave = (blockIdx.x * 256 + threadIdx.x) >> 6;
    int lane = threadIdx.x & 63;
    if (wave >= n) return;
    int e0 = row_start[wave], e1 = row_start[wave + 1];
    float a0 = 0.0f, a1 = 0.0f, a2 = 0.0f, a3 = 0.0f;
    float a4 = 0.0f, a5 = 0.0f, a6 = 0.0f, a7 = 0.0f;
    int e = e0;
    for (; e + 7 < e1; e += 8) {
        int2 d0 = sedge[e];
        int2 d1 = sedge[e + 1];
        int2 d2 = sedge[e + 2];
        int2 d3 = sedge[e + 3];
        int2 d4 = sedge[e + 4];
        int2 d5 = sedge[e + 5];
        int2 d6 = sedge[e + 6];
        int2 d7 = sedge[e + 7];
        float x0 = x[(size_t)d0.x * NCLASS + lane];
        float x1 = x[(size_t)d1.x * NCLASS + lane];
        float x2 = x[(size_t)d2.x * NCLASS + lane];
        float x3 = x[(size_t)d3.x * NCLASS + lane];
        float x4 = x[(size_t)d4.x * NCLASS + lane];
        float x5 = x[(size_t)d5.x * NCLASS + lane];
        float x6 = x[(size_t)d6.x * NCLASS + lane];
        float x7 = x[(size_t)d7.x * NCLASS + lane];
        a0 = fmaf(__int_as_float(d0.y), x0, a0);
        a1 = fmaf(__int_as_float(d1.y), x1, a1);
        a2 = fmaf(__int_as_float(d2.y), x2, a2);
        a3 = fmaf(__int_as_float(d3.y), x3, a3);
        a4 = fmaf(__int_as_float(d4.y), x4, a4);
        a5 = fmaf(__int_as_float(d5.y), x5, a5);
        a6 = fmaf(__int_as_float(d6.y), x6, a6);
        a7 = fmaf(__int_as_float(d7.y), x7, a7);
    }
    for (; e + 3 < e1; e += 4) {
        int2 d0 = sedge[e];
        int2 d1 = sedge[e + 1];
        int2 d2 = sedge[e + 2];
        int2 d3 = sedge[e + 3];
        float x0 = x[(size_t)d0.x * NCLASS + lane];
        float x1 = x[(size_t)d1.x * NCLASS + lane];
        float x2 = x[(size_t)d2.x * NCLASS + lane];
        float x3 = x[(size_t)d3.x * NCLASS + lane];
        a0 = fmaf(__int_as_float(d0.y), x0, a0);
        a1 = fmaf(__int_as_float(d1.y), x1, a1);
        a2 = fmaf(__int_as_float(d2.y), x2, a2);
        a3 = fmaf(__int_as_float(d3.y), x3, a3);
    }
    for (; e < e1; ++e) {
        int2 d = sedge[e];
        a0 = fmaf(__int_as_float(d.y), x[(size_t)d.x * NCLASS + lane], a0);
    }
    float acc = ((a0 + a1) + (a2 + a3)) + ((a4 + a5) + (a6 + a7));
    int o = wave * NCLASS + lane;
    y[o] = acc;
    finalbuf[o] += weight[wave * DEGREE + wcol] * acc;
}

__global__ __launch_bounds__(256) void logsoftmax_inplace(float* __restrict__ out, int n) {
    int wave = (blockIdx.x * 256 + threadIdx.x) >> 6;
    int lane = threadIdx.x & 63;
    if (wave >= n) return;
    int o = wave * NCLASS + lane;
    float x = out[o];
    float m = x;
    #pragma unroll
    for (int off = 1; off < 64; off <<= 1) m = fmaxf(m, __shfl_xor(m, off));
    float p = expf(x - m);
    float s = p;
    #pragma unroll
    for (int off = 1; off < 64; off <<= 1) s += __shfl_xor(s, off);
    out[o] = x - m - logf(s);
}

// ---------------- launch ----------------

extern "C" void kernel_launch(void* const* d_in, const int* in_sizes, int n_in,
                              void* d_out, int out_size, void* d_ws, size_t ws_size,
                              hipStream_t stream) {
    const float* f_pred = (const float*)d_in[0];
    const float* g0     = (const float*)d_in[1];
    const int*   arows  = (const int*)d_in[2];
    const int*   acols  = (const int*)d_in[3];
    const float* avals  = (const float*)d_in[4];
    const float* W1     = (const float*)d_in[5];
    const float* b1     = (const float*)d_in[6];
    const float* W2     = (const float*)d_in[7];
    const float* b2     = (const float*)d_in[8];
    const float* W3     = (const float*)d_in[9];
    const float* b3     = (const float*)d_in[10];

    float* out_ls = (float*)d_out;                                   // [N,64] final -> log_softmax
    float* weight = (float*)d_out + (size_t)N_NODES * NCLASS;        // [N,9]

    char* ws = (char*)d_ws;
    size_t off = 0;
    auto alloc = [&](size_t bytes) {
        void* p = ws + off;
        off += (bytes + 255) & ~(size_t)255;
        return p;
    };
    float* ranked    = (float*)alloc((size_t)N_NODES * TOPK * 4);
    float* fA        = (float*)alloc((size_t)N_NODES * NCLASS * 4);
    float* fB        = (float*)alloc((size_t)N_NODES * NCLASS * 4);
    int*   counts    = (int*)alloc((size_t)N_NODES * 4);
    int*   partial   = (int*)alloc((size_t)N_NODES * 4);
    int*   row_start = (int*)alloc((size_t)(N_NODES + 1) * 4);
    int*   cursor    = (int*)alloc((size_t)N_NODES * 4);
    int*   blocksums = (int*)alloc(128 * 4);
    int2*  sedge     = (int2*)alloc((size_t)NEDGE * 8);

    const int SCAN_BLOCKS = (N_NODES + 1023) / 1024;  // 98

    // CSR build
    hipMemsetAsync(counts, 0, (size_t)N_NODES * 4, stream);
    hist_kernel<<<2048, 256, 0, stream>>>(arows, counts, NEDGE);
    scan_blocks<<<SCAN_BLOCKS, 1024, 0, stream>>>(counts, partial, blocksums, N_NODES);
    scan_sums<<<1, 64, 0, stream>>>(blocksums, SCAN_BLOCKS);
    finalize_rows<<<(N_NODES + 255) / 256, 256, 0, stream>>>(partial, blocksums, row_start, cursor,
                                                             N_NODES, NEDGE);
    scatter_edges<<<2048, 256, 0, stream>>>(arows, acols, avals, cursor, sedge, NEDGE);

    // gating MLP
    softmax_topk<<<(N_NODES + 3) / 4, 256, 0, stream>>>(g0, ranked, N_NODES);
    mlp_kernel<<<(N_NODES + TM - 1) / TM, 256, 0, stream>>>(ranked, W1, b1, W2, b2, W3, b3,
                                                            weight, N_NODES);

    // final = w0 * f ; then 8 chained spmm with fused accumulation
    init_final<<<(N_NODES * NCLASS + 255) / 256, 256, 0, stream>>>(f_pred, weight, out_ls, N_NODES);

    const float* xin = f_pred;
    float* bufs[2] = {fA, fB};
    for (int it = 0; it < DEGREE - 1; ++it) {
        float* y = bufs[it & 1];
        spmm_fused<<<(N_NODES + 3) / 4, 256, 0, stream>>>(row_start, sedge, xin, y, weight, out_ls,
                                                          it + 1, N_NODES);
        xin = y;
    }

    logsoftmax_inplace<<<(N_NODES + 3) / 4, 256, 0, stream>>>(out_ls, N_NODES);
}

// Round 6
// 1290.846 us; speedup vs baseline: 1.6246x; 1.0666x over previous
//
#include <hip/hip_runtime.h>
#include <hip/hip_bf16.h>

#define N_NODES 100000
#define NCLASS  64
#define NEDGE   1600000
#define NHID    256
#define TOPK    16
#define DEGREE  9

#define TM 32            // rows per block in MLP
#define H2PAD (NHID + 4)

typedef __attribute__((ext_vector_type(8))) short bf16x8;
typedef __attribute__((ext_vector_type(4))) float f32x4;

__device__ __forceinline__ float fast_tanh(float x) {
    float e = __expf(2.0f * x);
    return 1.0f - 2.0f / (e + 1.0f);
}

// round-to-nearest-even fp32 -> bf16 bits
__device__ __forceinline__ ushort bf16_hi(float x) {
    uint u = __float_as_uint(x);
    uint r = (u + 0x7FFFu + ((u >> 16) & 1u)) >> 16;
    return (ushort)r;
}
__device__ __forceinline__ float bf16_tof(ushort h) {
    return __uint_as_float(((uint)h) << 16);
}

// ---------------- CSR build ----------------

__global__ void hist_kernel(const int* __restrict__ rows, int* __restrict__ counts, int e) {
    for (int i = blockIdx.x * blockDim.x + threadIdx.x; i < e; i += gridDim.x * blockDim.x)
        atomicAdd(&counts[rows[i]], 1);
}

__global__ __launch_bounds__(1024) void scan_blocks(const int* __restrict__ counts,
                                                    int* __restrict__ partial,
                                                    int* __restrict__ blocksums, int n) {
    __shared__ int s[1024];
    int tid = threadIdx.x;
    int gid = blockIdx.x * 1024 + tid;
    int v = (gid < n) ? counts[gid] : 0;
    s[tid] = v;
    __syncthreads();
    for (int off = 1; off < 1024; off <<= 1) {
        int t = (tid >= off) ? s[tid - off] : 0;
        __syncthreads();
        s[tid] += t;
        __syncthreads();
    }
    if (gid < n) partial[gid] = s[tid] - v;  // exclusive
    if (tid == 1023) blocksums[blockIdx.x] = s[1023];
}

__global__ void scan_sums(int* __restrict__ blocksums, int nb) {
    if (blockIdx.x == 0 && threadIdx.x == 0) {
        int run = 0;
        for (int i = 0; i < nb; ++i) { int v = blocksums[i]; blocksums[i] = run; run += v; }
    }
}

__global__ void finalize_rows(const int* __restrict__ partial, const int* __restrict__ blocksums,
                              int* __restrict__ row_start, int* __restrict__ cursor, int n, int e) {
    int i = blockIdx.x * blockDim.x + threadIdx.x;
    if (i < n) {
        int v = partial[i] + blocksums[i >> 10];
        row_start[i] = v;
        cursor[i] = v;
    }
    if (i == 0) row_start[n] = e;
}

__global__ void scatter_edges(const int* __restrict__ rows, const int* __restrict__ cols,
                              const float* __restrict__ vals, int* __restrict__ cursor,
                              int2* __restrict__ sedge, int e) {
    for (int i = blockIdx.x * blockDim.x + threadIdx.x; i < e; i += gridDim.x * blockDim.x) {
        int r = rows[i];
        int pos = atomicAdd(&cursor[r], 1);
        sedge[pos] = make_int2(cols[i], __float_as_int(vals[i]));
    }
}

// ---------------- softmax + top-16 (wave per row) ----------------

__global__ __launch_bounds__(256) void softmax_topk(const float* __restrict__ g0,
                                                    float* __restrict__ ranked, int n) {
    int wave = (blockIdx.x * 256 + threadIdx.x) >> 6;
    int lane = threadIdx.x & 63;
    if (wave >= n) return;
    float x = g0[(size_t)wave * NCLASS + lane];
    float m = x;
    #pragma unroll
    for (int o = 1; o < 64; o <<= 1) m = fmaxf(m, __shfl_xor(m, o));
    float p = expf(x - m);
    float s = p;
    #pragma unroll
    for (int o = 1; o < 64; o <<= 1) s += __shfl_xor(s, o);
    p /= s;
    float v = p;
    #pragma unroll
    for (int k = 2; k <= 64; k <<= 1) {
        #pragma unroll
        for (int j = k >> 1; j > 0; j >>= 1) {
            float o = __shfl_xor(v, j);
            bool up = (lane & k) != 0;
            bool takeMax = (((lane & j) == 0) != up);
            v = takeMax ? fmaxf(v, o) : fminf(v, o);
        }
    }
    if (lane < TOPK) ranked[wave * TOPK + lane] = v;
}

// ---------------- W2 -> bf16 hi/lo MFMA B-fragments (one-time prep) ----------------
// Fragment layout for v_mfma_f32_16x16x32_bf16 B-operand:
//   elem j of lane l in tile (ks, nt) = W2[32*ks + (l>>4)*8 + j][16*nt + (l&15)]
// Stored flat: frag[((ks*16 + nt)*64 + l)*8 + j] so the kernel's load is a
// coalesced 16B-per-lane dwordx4.

__global__ __launch_bounds__(256) void w2frag_build(const float* __restrict__ W2,
                                                    ushort* __restrict__ fhi,
                                                    ushort* __restrict__ flo) {
    int idx = blockIdx.x * 256 + threadIdx.x;   // (ks*16+nt)*64 + lane, 16384 total
    if (idx >= 16 * 16 * 64) return;
    int l = idx & 63;
    int tile = idx >> 6;
    int nt = tile & 15, ks = tile >> 4;
    int col = nt * 16 + (l & 15);
    int krow = ks * 32 + (l >> 4) * 8;
    #pragma unroll
    for (int j = 0; j < 8; ++j) {
        float wv = W2[(size_t)(krow + j) * NHID + col];
        ushort h = bf16_hi(wv);
        float res = wv - bf16_tof(h);
        fhi[(size_t)idx * 8 + j] = h;
        flo[(size_t)idx * 8 + j] = bf16_hi(res);
    }
}

// ---------------- MLP: [N,16] -> 512 (VALU) -> 256 (MFMA bf16x3) -> 9 (VALU) ----
// h1 stored in LDS as bf16 hi/lo, XOR-swizzled (byte ^= (row&7)<<4) so the
// A-fragment ds_read_b128 (row-stride 1024B) is bank-conflict-free.
// Layer2: 3-pass split product Ah*Bh + Ah*Bl + Al*Bh -> ~2^-18 rel error.
// C/D layout (m89-verified): col = lane&15, row = (lane>>4)*4 + reg.

__global__ __launch_bounds__(256) void mlp_kernel(const float* __restrict__ ranked,
                                                  const float* __restrict__ W1, const float* __restrict__ b1,
                                                  const ushort* __restrict__ w2fh,
                                                  const ushort* __restrict__ w2fl,
                                                  const float* __restrict__ b2,
                                                  const float* __restrict__ W3, const float* __restrict__ b3,
                                                  float* __restrict__ weight_out, int n) {
    __shared__ float s_rank[TM][TOPK];            // 2 KB
    __shared__ ushort s_h1[2][TM][2 * NHID];      // 64 KB: [hi/lo][row][k]
    // s_h2 aliases s_h1 (used strictly after a barrier once A-frags are consumed)
    float (*s_h2)[H2PAD] = reinterpret_cast<float (*)[H2PAD]>(&s_h1[0][0][0]);

    const int t = threadIdx.x;
    const int row0 = blockIdx.x * TM;
    char* h1base = reinterpret_cast<char*>(&s_h1[0][0][0]);
    const uint LOBYTES = TM * 2 * NHID * 2;       // 32768: offset of lo plane

    for (int idx = t; idx < TM * TOPK; idx += 256) {
        int r = idx >> 4, k = idx & 15;
        int gr = row0 + r;
        s_rank[r][k] = (gr < n) ? ranked[gr * TOPK + k] : 0.0f;
    }
    __syncthreads();

    // ---- layer 1: thread owns h1 cols t and t+256, all 32 rows ----
    {
        float w1a[TOPK], w1b[TOPK];
        #pragma unroll
        for (int k = 0; k < TOPK; ++k) {
            w1a[k] = W1[k * (2 * NHID) + t];
            w1b[k] = W1[k * (2 * NHID) + t + NHID];
        }
        float ba = b1[t], bb = b1[t + NHID];
        for (int r = 0; r < TM; ++r) {
            float4 q0 = *reinterpret_cast<const float4*>(&s_rank[r][0]);
            float4 q1 = *reinterpret_cast<const float4*>(&s_rank[r][4]);
            float4 q2 = *reinterpret_cast<const float4*>(&s_rank[r][8]);
            float4 q3 = *reinterpret_cast<const float4*>(&s_rank[r][12]);
            float rk[TOPK] = {q0.x, q0.y, q0.z, q0.w, q1.x, q1.y, q1.z, q1.w,
                              q2.x, q2.y, q2.z, q2.w, q3.x, q3.y, q3.z, q3.w};
            float a = ba, b = bb;
            #pragma unroll
            for (int k = 0; k < TOPK; ++k) {
                a = fmaf(rk[k], w1a[k], a);
                b = fmaf(rk[k], w1b[k], b);
            }
            float ha = fast_tanh(a), hb = fast_tanh(b);
            ushort hah = bf16_hi(ha);
            ushort hal = bf16_hi(ha - bf16_tof(hah));
            ushort hbh = bf16_hi(hb);
            ushort hbl = bf16_hi(hb - bf16_tof(hbh));
            uint swz = (uint)(r & 7) << 4;
            uint offa = ((uint)(r * 1024 + t * 2)) ^ swz;
            uint offb = ((uint)(r * 1024 + (t + NHID) * 2)) ^ swz;
            *reinterpret_cast<ushort*>(h1base + offa) = hah;
            *reinterpret_cast<ushort*>(h1base + LOBYTES + offa) = hal;
            *reinterpret_cast<ushort*>(h1base + offb) = hbh;
            *reinterpret_cast<ushort*>(h1base + LOBYTES + offb) = hbl;
        }
    }
    __syncthreads();

    // ---- layer 2: MFMA. wave w: row-tile mt = w&1, col-tiles nt0..nt0+7 ----
    const int w = t >> 6, l = t & 63;
    const int mt = w & 1;
    const int nt0 = (w >> 1) * 8;
    f32x4 acc[8];
    #pragma unroll
    for (int nn = 0; nn < 8; ++nn) {
        float bv = b2[(nt0 + nn) * 16 + (l & 15)];
        acc[nn] = (f32x4){bv, bv, bv, bv};
    }
    const int arow = mt * 16 + (l & 15);
    const uint aswz = (uint)(arow & 7) << 4;
    for (int ks = 0; ks < 16; ++ks) {
        uint aoff = ((uint)(arow * 1024 + ks * 64 + (l >> 4) * 16)) ^ aswz;
        bf16x8 ah = *reinterpret_cast<const bf16x8*>(h1base + aoff);
        bf16x8 al = *reinterpret_cast<const bf16x8*>(h1base + LOBYTES + aoff);
        #pragma unroll
        for (int nn = 0; nn < 8; ++nn) {
            size_t boff = (size_t)(((ks * 16 + nt0 + nn) * 64 + l)) * 8;
            bf16x8 bh = *reinterpret_cast<const bf16x8*>(w2fh + boff);
            bf16x8 bl = *reinterpret_cast<const bf16x8*>(w2fl + boff);
            acc[nn] = __builtin_amdgcn_mfma_f32_16x16x32_bf16(ah, bh, acc[nn], 0, 0, 0);
            acc[nn] = __builtin_amdgcn_mfma_f32_16x16x32_bf16(ah, bl, acc[nn], 0, 0, 0);
            acc[nn] = __builtin_amdgcn_mfma_f32_16x16x32_bf16(al, bh, acc[nn], 0, 0, 0);
        }
    }
    __syncthreads();   // all A-frag reads done before s_h2 overwrites s_h1

    // ---- epilogue: h2 = tanh(acc) into s_h2 ----
    #pragma unroll
    for (int nn = 0; nn < 8; ++nn) {
        #pragma unroll
        for (int i = 0; i < 4; ++i) {
            int rr = mt * 16 + (l >> 4) * 4 + i;
            int cc = (nt0 + nn) * 16 + (l & 15);
            s_h2[rr][cc] = fast_tanh(acc[nn][i]);
        }
    }
    __syncthreads();

    // ---- layer 3: TM x 9 = 288 outputs, float4 k-unroll ----
    for (int idx = t; idx < TM * DEGREE; idx += 256) {
        int r = idx / DEGREE, d = idx % DEGREE;
        float a3 = b3[d];
        for (int k = 0; k < NHID; k += 4) {
            float4 h = *reinterpret_cast<const float4*>(&s_h2[r][k]);
            a3 = fmaf(h.x, W3[(k + 0) * DEGREE + d], a3);
            a3 = fmaf(h.y, W3[(k + 1) * DEGREE + d], a3);
            a3 = fmaf(h.z, W3[(k + 2) * DEGREE + d], a3);
            a3 = fmaf(h.w, W3[(k + 3) * DEGREE + d], a3);
        }
        int gr = row0 + r;
        if (gr < n) weight_out[gr * DEGREE + d] = a3;
    }
}

// ---------------- final init + SpMM chain ----------------

__global__ void init_final(const float* __restrict__ fpred, const float* __restrict__ weight,
                           float* __restrict__ finalbuf, int n) {
    int i = blockIdx.x * blockDim.x + threadIdx.x;
    if (i < n * NCLASS) {
        int row = i >> 6;
        finalbuf[i] = weight[row * DEGREE] * fpred[i];
    }
}

// wave per row, lane = feature; always-8-wide clamp-masked gather loop
// (no serial remainder tail: clamped edges reload the last edge -> L1 hit,
// masked val=0 keeps the sum exact)
__global__ __launch_bounds__(256) void spmm_fused(const int* __restrict__ row_start,
                                                  const int2* __restrict__ sedge,
                                                  const float* __restrict__ x,
                                                  float* __restrict__ y,
                                                  const float* __restrict__ weight,
                                                  float* __restrict__ finalbuf,
                                                  int wcol, int n) {
    int wave = (blockIdx.x * 256 + threadIdx.x) >> 6;
    int lane = threadIdx.x & 63;
    if (wave >= n) return;
    int e0 = row_start[wave], e1 = row_start[wave + 1];
    float a[8] = {0.0f, 0.0f, 0.0f, 0.0f, 0.0f, 0.0f, 0.0f, 0.0f};
    for (int e = e0; e < e1; e += 8) {
        int2 dd[8];
        #pragma unroll
        for (int i = 0; i < 8; ++i) {
            int ei = (e + i < e1) ? (e + i) : (e1 - 1);
            dd[i] = sedge[ei];
        }
        float xv[8];
        #pragma unroll
        for (int i = 0; i < 8; ++i)
            xv[i] = x[(size_t)dd[i].x * NCLASS + lane];
        #pragma unroll
        for (int i = 0; i < 8; ++i) {
            float v = (e + i < e1) ? __int_as_float(dd[i].y) : 0.0f;
            a[i] = fmaf(v, xv[i], a[i]);
        }
    }
    float acc = ((a[0] + a[1]) + (a[2] + a[3])) + ((a[4] + a[5]) + (a[6] + a[7]));
    int o = wave * NCLASS + lane;
    y[o] = acc;
    finalbuf[o] += weight[wave * DEGREE + wcol] * acc;
}

__global__ __launch_bounds__(256) void logsoftmax_inplace(float* __restrict__ out, int n) {
    int wave = (blockIdx.x * 256 + threadIdx.x) >> 6;
    int lane = threadIdx.x & 63;
    if (wave >= n) return;
    int o = wave * NCLASS + lane;
    float x = out[o];
    float m = x;
    #pragma unroll
    for (int off = 1; off < 64; off <<= 1) m = fmaxf(m, __shfl_xor(m, off));
    float p = expf(x - m);
    float s = p;
    #pragma unroll
    for (int off = 1; off < 64; off <<= 1) s += __shfl_xor(s, off);
    out[o] = x - m - logf(s);
}

// ---------------- launch ----------------

extern "C" void kernel_launch(void* const* d_in, const int* in_sizes, int n_in,
                              void* d_out, int out_size, void* d_ws, size_t ws_size,
                              hipStream_t stream) {
    const float* f_pred = (const float*)d_in[0];
    const float* g0     = (const float*)d_in[1];
    const int*   arows  = (const int*)d_in[2];
    const int*   acols  = (const int*)d_in[3];
    const float* avals  = (const float*)d_in[4];
    const float* W1     = (const float*)d_in[5];
    const float* b1     = (const float*)d_in[6];
    const float* W2     = (const float*)d_in[7];
    const float* b2     = (const float*)d_in[8];
    const float* W3     = (const float*)d_in[9];
    const float* b3     = (const float*)d_in[10];

    float* out_ls = (float*)d_out;                                   // [N,64]
    float* weight = (float*)d_out + (size_t)N_NODES * NCLASS;        // [N,9]

    char* ws = (char*)d_ws;
    size_t off = 0;
    auto alloc = [&](size_t bytes) {
        void* p = ws + off;
        off += (bytes + 255) & ~(size_t)255;
        return p;
    };
    float*  ranked    = (float*)alloc((size_t)N_NODES * TOPK * 4);
    float*  fA        = (float*)alloc((size_t)N_NODES * NCLASS * 4);
    float*  fB        = (float*)alloc((size_t)N_NODES * NCLASS * 4);
    int*    counts    = (int*)alloc((size_t)N_NODES * 4);
    int*    partial   = (int*)alloc((size_t)N_NODES * 4);
    int*    row_start = (int*)alloc((size_t)(N_NODES + 1) * 4);
    int*    cursor    = (int*)alloc((size_t)N_NODES * 4);
    int*    blocksums = (int*)alloc(128 * 4);
    ushort* w2fh      = (ushort*)alloc((size_t)16 * 16 * 64 * 8 * 2);
    ushort* w2fl      = (ushort*)alloc((size_t)16 * 16 * 64 * 8 * 2);
    int2*   sedge     = (int2*)alloc((size_t)NEDGE * 8);

    const int SCAN_BLOCKS = (N_NODES + 1023) / 1024;  // 98

    // CSR build
    hipMemsetAsync(counts, 0, (size_t)N_NODES * 4, stream);
    hist_kernel<<<2048, 256, 0, stream>>>(arows, counts, NEDGE);
    scan_blocks<<<SCAN_BLOCKS, 1024, 0, stream>>>(counts, partial, blocksums, N_NODES);
    scan_sums<<<1, 64, 0, stream>>>(blocksums, SCAN_BLOCKS);
    finalize_rows<<<(N_NODES + 255) / 256, 256, 0, stream>>>(partial, blocksums, row_start, cursor,
                                                             N_NODES, NEDGE);
    scatter_edges<<<2048, 256, 0, stream>>>(arows, acols, avals, cursor, sedge, NEDGE);

    // gating MLP
    w2frag_build<<<64, 256, 0, stream>>>(W2, w2fh, w2fl);
    softmax_topk<<<(N_NODES + 3) / 4, 256, 0, stream>>>(g0, ranked, N_NODES);
    mlp_kernel<<<(N_NODES + TM - 1) / TM, 256, 0, stream>>>(ranked, W1, b1, w2fh, w2fl, b2,
                                                            W3, b3, weight, N_NODES);

    // final = w0 * f ; then 8 chained spmm with fused accumulation
    init_final<<<(N_NODES * NCLASS + 255) / 256, 256, 0, stream>>>(f_pred, weight, out_ls, N_NODES);

    const float* xin = f_pred;
    float* bufs[2] = {fA, fB};
    for (int it = 0; it < DEGREE - 1; ++it) {
        float* y = bufs[it & 1];
        spmm_fused<<<(N_NODES + 3) / 4, 256, 0, stream>>>(row_start, sedge, xin, y, weight, out_ls,
                                                          it + 1, N_NODES);
        xin = y;
    }

    logsoftmax_inplace<<<(N_NODES + 3) / 4, 256, 0, stream>>>(out_ls, N_NODES);
}

// Round 7
// 1215.575 us; speedup vs baseline: 1.7252x; 1.0619x over previous
//
#include <hip/hip_runtime.h>
#include <hip/hip_bf16.h>

#define N_NODES 100000
#define NCLASS  64
#define NEDGE   1600000
#define NHID    256
#define TOPK    16
#define DEGREE  9

#define TM 32            // rows per block in MLP
#define H2PAD (NHID + 4)

typedef __attribute__((ext_vector_type(8))) short bf16x8;
typedef __attribute__((ext_vector_type(4))) float f32x4;

__device__ __forceinline__ float fast_tanh(float x) {
    float e = __expf(2.0f * x);
    return 1.0f - 2.0f / (e + 1.0f);
}

// round-to-nearest-even fp32 -> bf16 bits
__device__ __forceinline__ ushort bf16_hi(float x) {
    uint u = __float_as_uint(x);
    uint r = (u + 0x7FFFu + ((u >> 16) & 1u)) >> 16;
    return (ushort)r;
}
__device__ __forceinline__ float bf16_tof(ushort h) {
    return __uint_as_float(((uint)h) << 16);
}

// ---------------- CSR build ----------------

__global__ void hist_kernel(const int* __restrict__ rows, int* __restrict__ counts, int e) {
    for (int i = blockIdx.x * blockDim.x + threadIdx.x; i < e; i += gridDim.x * blockDim.x)
        atomicAdd(&counts[rows[i]], 1);
}

__global__ __launch_bounds__(1024) void scan_blocks(const int* __restrict__ counts,
                                                    int* __restrict__ partial,
                                                    int* __restrict__ blocksums, int n) {
    __shared__ int s[1024];
    int tid = threadIdx.x;
    int gid = blockIdx.x * 1024 + tid;
    int v = (gid < n) ? counts[gid] : 0;
    s[tid] = v;
    __syncthreads();
    for (int off = 1; off < 1024; off <<= 1) {
        int t = (tid >= off) ? s[tid - off] : 0;
        __syncthreads();
        s[tid] += t;
        __syncthreads();
    }
    if (gid < n) partial[gid] = s[tid] - v;  // exclusive
    if (tid == 1023) blocksums[blockIdx.x] = s[1023];
}

__global__ void scan_sums(int* __restrict__ blocksums, int nb) {
    if (blockIdx.x == 0 && threadIdx.x == 0) {
        int run = 0;
        for (int i = 0; i < nb; ++i) { int v = blocksums[i]; blocksums[i] = run; run += v; }
    }
}

__global__ void finalize_rows(const int* __restrict__ partial, const int* __restrict__ blocksums,
                              int* __restrict__ row_start, int* __restrict__ cursor, int n, int e) {
    int i = blockIdx.x * blockDim.x + threadIdx.x;
    if (i < n) {
        int v = partial[i] + blocksums[i >> 10];
        row_start[i] = v;
        cursor[i] = v;
    }
    if (i == 0) row_start[n] = e;
}

// stores col pre-scaled to element offset (col*NCLASS) so the spmm gather
// needs no per-edge multiply
__global__ void scatter_edges(const int* __restrict__ rows, const int* __restrict__ cols,
                              const float* __restrict__ vals, int* __restrict__ cursor,
                              int2* __restrict__ sedge, int e) {
    for (int i = blockIdx.x * blockDim.x + threadIdx.x; i < e; i += gridDim.x * blockDim.x) {
        int r = rows[i];
        int pos = atomicAdd(&cursor[r], 1);
        sedge[pos] = make_int2(cols[i] * NCLASS, __float_as_int(vals[i]));
    }
}

// ---------------- softmax + top-16 (wave per row) ----------------

__global__ __launch_bounds__(256) void softmax_topk(const float* __restrict__ g0,
                                                    float* __restrict__ ranked, int n) {
    int wave = (blockIdx.x * 256 + threadIdx.x) >> 6;
    int lane = threadIdx.x & 63;
    if (wave >= n) return;
    float x = g0[(size_t)wave * NCLASS + lane];
    float m = x;
    #pragma unroll
    for (int o = 1; o < 64; o <<= 1) m = fmaxf(m, __shfl_xor(m, o));
    float p = expf(x - m);
    float s = p;
    #pragma unroll
    for (int o = 1; o < 64; o <<= 1) s += __shfl_xor(s, o);
    p /= s;
    float v = p;
    #pragma unroll
    for (int k = 2; k <= 64; k <<= 1) {
        #pragma unroll
        for (int j = k >> 1; j > 0; j >>= 1) {
            float o = __shfl_xor(v, j);
            bool up = (lane & k) != 0;
            bool takeMax = (((lane & j) == 0) != up);
            v = takeMax ? fmaxf(v, o) : fminf(v, o);
        }
    }
    if (lane < TOPK) ranked[wave * TOPK + lane] = v;
}

// ---------------- prep: W2 -> bf16 hi/lo MFMA B-fragments, W3 -> W3^T ----------------
// B-frag elem j of lane l in tile (ks, nt) = W2[32*ks + (l>>4)*8 + j][16*nt + (l&15)]
// flat: frag[((ks*16 + nt)*64 + l)*8 + j] -> kernel load = coalesced dwordx4/lane.

__global__ __launch_bounds__(256) void w2frag_build(const float* __restrict__ W2,
                                                    ushort* __restrict__ fhi,
                                                    ushort* __restrict__ flo) {
    int idx = blockIdx.x * 256 + threadIdx.x;   // (ks*16+nt)*64 + lane, 16384 total
    if (idx >= 16 * 16 * 64) return;
    int l = idx & 63;
    int tile = idx >> 6;
    int nt = tile & 15, ks = tile >> 4;
    int col = nt * 16 + (l & 15);
    int krow = ks * 32 + (l >> 4) * 8;
    #pragma unroll
    for (int j = 0; j < 8; ++j) {
        float wv = W2[(size_t)(krow + j) * NHID + col];
        ushort h = bf16_hi(wv);
        float res = wv - bf16_tof(h);
        fhi[(size_t)idx * 8 + j] = h;
        flo[(size_t)idx * 8 + j] = bf16_hi(res);
    }
}

__global__ void w3t_build(const float* __restrict__ W3, float* __restrict__ W3t) {
    int i = blockIdx.x * 256 + threadIdx.x;
    if (i < NHID * DEGREE) {
        int d = i / NHID, k = i % NHID;
        W3t[d * NHID + k] = W3[k * DEGREE + d];
    }
}

// ---------------- MLP: [N,16] -> 512 (VALU) -> 256 (MFMA bf16x3) -> 9 (VALU) ----
// h1 in LDS as bf16 hi/lo planes, XOR-swizzled (byte ^= (row&7)<<4) so the
// A-frag ds_read_b128 at row-stride 1024B is conflict-free.
// Layer2: 3-pass split Ah*Bh + Ah*Bl + Al*Bh (~2^-18 rel), B-frags double-
// buffered one ks ahead to hide L2 latency. C/D: col=lane&15, row=(lane>>4)*4+reg.

__global__ __launch_bounds__(256) void mlp_kernel(const float* __restrict__ ranked,
                                                  const float* __restrict__ W1, const float* __restrict__ b1,
                                                  const ushort* __restrict__ w2fh,
                                                  const ushort* __restrict__ w2fl,
                                                  const float* __restrict__ b2,
                                                  const float* __restrict__ W3t, const float* __restrict__ b3,
                                                  float* __restrict__ weight_out, int n) {
    __shared__ float s_rank[TM][TOPK];            // 2 KB
    __shared__ ushort s_h1[2][TM][2 * NHID];      // 64 KB: [hi/lo][row][k]
    float (*s_h2)[H2PAD] = reinterpret_cast<float (*)[H2PAD]>(&s_h1[0][0][0]); // aliased after barrier

    const int t = threadIdx.x;
    const int row0 = blockIdx.x * TM;
    char* h1base = reinterpret_cast<char*>(&s_h1[0][0][0]);
    const uint LOBYTES = TM * 2 * NHID * 2;       // 32768

    for (int idx = t; idx < TM * TOPK; idx += 256) {
        int r = idx >> 4, k = idx & 15;
        int gr = row0 + r;
        s_rank[r][k] = (gr < n) ? ranked[gr * TOPK + k] : 0.0f;
    }
    __syncthreads();

    // ---- layer 1: thread owns adjacent cols 2t, 2t+1; packed u32 stores ----
    {
        float w1a[TOPK], w1b[TOPK];
        #pragma unroll
        for (int k = 0; k < TOPK; ++k) {
            float2 wv = *reinterpret_cast<const float2*>(&W1[k * (2 * NHID) + 2 * t]);
            w1a[k] = wv.x; w1b[k] = wv.y;
        }
        float2 b12 = *reinterpret_cast<const float2*>(&b1[2 * t]);
        for (int r = 0; r < TM; ++r) {
            float4 q0 = *reinterpret_cast<const float4*>(&s_rank[r][0]);
            float4 q1 = *reinterpret_cast<const float4*>(&s_rank[r][4]);
            float4 q2 = *reinterpret_cast<const float4*>(&s_rank[r][8]);
            float4 q3 = *reinterpret_cast<const float4*>(&s_rank[r][12]);
            float rk[TOPK] = {q0.x, q0.y, q0.z, q0.w, q1.x, q1.y, q1.z, q1.w,
                              q2.x, q2.y, q2.z, q2.w, q3.x, q3.y, q3.z, q3.w};
            float a = b12.x, b = b12.y;
            #pragma unroll
            for (int k = 0; k < TOPK; ++k) {
                a = fmaf(rk[k], w1a[k], a);
                b = fmaf(rk[k], w1b[k], b);
            }
            float ha = fast_tanh(a), hb = fast_tanh(b);
            ushort hah = bf16_hi(ha);
            ushort hal = bf16_hi(ha - bf16_tof(hah));
            ushort hbh = bf16_hi(hb);
            ushort hbl = bf16_hi(hb - bf16_tof(hbh));
            uint offa = ((uint)(r * 1024 + t * 4)) ^ ((uint)(r & 7) << 4);
            *reinterpret_cast<uint*>(h1base + offa) = (uint)hah | ((uint)hbh << 16);
            *reinterpret_cast<uint*>(h1base + LOBYTES + offa) = (uint)hal | ((uint)hbl << 16);
        }
    }
    __syncthreads();

    // ---- layer 2: MFMA, B-frags double-buffered one ks ahead ----
    const int w = t >> 6, l = t & 63;
    const int mt = w & 1;
    const int nt0 = (w >> 1) * 8;
    f32x4 acc[8];
    #pragma unroll
    for (int nn = 0; nn < 8; ++nn) {
        float bv = b2[(nt0 + nn) * 16 + (l & 15)];
        acc[nn] = (f32x4){bv, bv, bv, bv};
    }
    const int arow = mt * 16 + (l & 15);
    const uint aswz = (uint)(arow & 7) << 4;
    const uint abase = (uint)(arow * 1024 + (l >> 4) * 16);
    const ushort* bhp = w2fh + (size_t)nt0 * 512 + (size_t)l * 8;
    const ushort* blp = w2fl + (size_t)nt0 * 512 + (size_t)l * 8;

    bf16x8 bAh[8], bAl[8], bBh[8], bBl[8];
    #pragma unroll
    for (int nn = 0; nn < 8; ++nn) {
        bAh[nn] = *reinterpret_cast<const bf16x8*>(bhp + nn * 512);
        bAl[nn] = *reinterpret_cast<const bf16x8*>(blp + nn * 512);
    }

#define L2STEP(CURH, CURL, NXTH, NXTL, KS)                                             \
    {                                                                                  \
        uint aoff = (abase + (uint)(KS) * 64) ^ aswz;                                  \
        bf16x8 ah = *reinterpret_cast<const bf16x8*>(h1base + aoff);                   \
        bf16x8 al = *reinterpret_cast<const bf16x8*>(h1base + LOBYTES + aoff);         \
        if ((KS) < 15) {                                                               \
            const ushort* ph = bhp + (size_t)((KS) + 1) * 8192;                        \
            const ushort* pl = blp + (size_t)((KS) + 1) * 8192;                        \
            _Pragma("unroll")                                                          \
            for (int nn = 0; nn < 8; ++nn) {                                           \
                NXTH[nn] = *reinterpret_cast<const bf16x8*>(ph + nn * 512);            \
                NXTL[nn] = *reinterpret_cast<const bf16x8*>(pl + nn * 512);            \
            }                                                                          \
        }                                                                              \
        _Pragma("unroll")                                                              \
        for (int nn = 0; nn < 8; ++nn) {                                               \
            acc[nn] = __builtin_amdgcn_mfma_f32_16x16x32_bf16(ah, CURH[nn], acc[nn], 0, 0, 0); \
            acc[nn] = __builtin_amdgcn_mfma_f32_16x16x32_bf16(ah, CURL[nn], acc[nn], 0, 0, 0); \
            acc[nn] = __builtin_amdgcn_mfma_f32_16x16x32_bf16(al, CURH[nn], acc[nn], 0, 0, 0); \
        }                                                                              \
    }

    for (int ks = 0; ks < 16; ks += 2) {
        L2STEP(bAh, bAl, bBh, bBl, ks)
        L2STEP(bBh, bBl, bAh, bAl, ks + 1)
    }
#undef L2STEP
    __syncthreads();   // all A-frag reads done before s_h2 overwrites s_h1

    // ---- epilogue: h2 = tanh(acc) into s_h2 ----
    #pragma unroll
    for (int nn = 0; nn < 8; ++nn) {
        #pragma unroll
        for (int i = 0; i < 4; ++i) {
            int rr = mt * 16 + (l >> 4) * 4 + i;
            int cc = (nt0 + nn) * 16 + (l & 15);
            s_h2[rr][cc] = fast_tanh(acc[nn][i]);
        }
    }
    __syncthreads();

    // ---- layer 3: TM x 9 = 288 outputs, float4 both sides via W3^T ----
    for (int idx = t; idx < TM * DEGREE; idx += 256) {
        int r = idx / DEGREE, d = idx % DEGREE;
        const float* wt = W3t + d * NHID;
        float a3 = b3[d];
        for (int k = 0; k < NHID; k += 4) {
            float4 h = *reinterpret_cast<const float4*>(&s_h2[r][k]);
            float4 wv = *reinterpret_cast<const float4*>(&wt[k]);
            a3 = fmaf(h.x, wv.x, a3);
            a3 = fmaf(h.y, wv.y, a3);
            a3 = fmaf(h.z, wv.z, a3);
            a3 = fmaf(h.w, wv.w, a3);
        }
        int gr = row0 + r;
        if (gr < n) weight_out[gr * DEGREE + d] = a3;
    }
}

// ---------------- SpMM chain (fused init / accumulate / log_softmax) ----------------
// wave per row, lane = feature; 16-wide then 8-wide then serial-tail gather ILP.
// MODE 0: finalbuf = w0*fpred + w1*acc   (first hop, absorbs init_final)
// MODE 1: finalbuf += w_wcol*acc
// MODE 2: final += w8*acc, then in-wave log_softmax (last hop, absorbs epilogue)

template<int MODE>
__global__ __launch_bounds__(256) void spmm_fused(const int* __restrict__ row_start,
                                                  const int2* __restrict__ sedge,
                                                  const float* __restrict__ x,
                                                  float* __restrict__ y,
                                                  const float* __restrict__ weight,
                                                  float* __restrict__ finalbuf,
                                                  const float* __restrict__ fpred,
                                                  int wcol, int n) {
    int row = (blockIdx.x * 256 + threadIdx.x) >> 6;
    int lane = threadIdx.x & 63;
    if (row >= n) return;
    int e0 = row_start[row], e1 = row_start[row + 1];
    float a[16];
    #pragma unroll
    for (int i = 0; i < 16; ++i) a[i] = 0.0f;
    int e = e0;
    for (; e + 15 < e1; e += 16) {
        int2 d[16];
        #pragma unroll
        for (int i = 0; i < 16; ++i) d[i] = sedge[e + i];
        float xv[16];
        #pragma unroll
        for (int i = 0; i < 16; ++i) xv[i] = x[(uint)d[i].x + lane];
        #pragma unroll
        for (int i = 0; i < 16; ++i) a[i] = fmaf(__int_as_float(d[i].y), xv[i], a[i]);
    }
    for (; e + 7 < e1; e += 8) {
        int2 d[8];
        #pragma unroll
        for (int i = 0; i < 8; ++i) d[i] = sedge[e + i];
        float xv[8];
        #pragma unroll
        for (int i = 0; i < 8; ++i) xv[i] = x[(uint)d[i].x + lane];
        #pragma unroll
        for (int i = 0; i < 8; ++i) a[i] = fmaf(__int_as_float(d[i].y), xv[i], a[i]);
    }
    for (; e < e1; ++e) {
        int2 d = sedge[e];
        a[0] = fmaf(__int_as_float(d.y), x[(uint)d.x + lane], a[0]);
    }
    float acc = (((a[0] + a[1]) + (a[2] + a[3])) + ((a[4] + a[5]) + (a[6] + a[7])))
              + (((a[8] + a[9]) + (a[10] + a[11])) + ((a[12] + a[13]) + (a[14] + a[15])));
    int o = row * NCLASS + lane;
    if (MODE == 0) {
        y[o] = acc;
        finalbuf[o] = weight[row * DEGREE] * fpred[o] + weight[row * DEGREE + 1] * acc;
    } else if (MODE == 1) {
        y[o] = acc;
        finalbuf[o] += weight[row * DEGREE + wcol] * acc;
    } else {
        float v = finalbuf[o] + weight[row * DEGREE + (DEGREE - 1)] * acc;
        float m = v;
        #pragma unroll
        for (int off = 1; off < 64; off <<= 1) m = fmaxf(m, __shfl_xor(m, off));
        float p = expf(v - m);
        float s = p;
        #pragma unroll
        for (int off = 1; off < 64; off <<= 1) s += __shfl_xor(s, off);
        finalbuf[o] = v - m - logf(s);
    }
}

// ---------------- launch ----------------

extern "C" void kernel_launch(void* const* d_in, const int* in_sizes, int n_in,
                              void* d_out, int out_size, void* d_ws, size_t ws_size,
                              hipStream_t stream) {
    const float* f_pred = (const float*)d_in[0];
    const float* g0     = (const float*)d_in[1];
    const int*   arows  = (const int*)d_in[2];
    const int*   acols  = (const int*)d_in[3];
    const float* avals  = (const float*)d_in[4];
    const float* W1     = (const float*)d_in[5];
    const float* b1     = (const float*)d_in[6];
    const float* W2     = (const float*)d_in[7];
    const float* b2     = (const float*)d_in[8];
    const float* W3     = (const float*)d_in[9];
    const float* b3     = (const float*)d_in[10];

    float* out_ls = (float*)d_out;                                   // [N,64]
    float* weight = (float*)d_out + (size_t)N_NODES * NCLASS;        // [N,9]

    char* ws = (char*)d_ws;
    size_t off = 0;
    auto alloc = [&](size_t bytes) {
        void* p = ws + off;
        off += (bytes + 255) & ~(size_t)255;
        return p;
    };
    float*  ranked    = (float*)alloc((size_t)N_NODES * TOPK * 4);
    float*  fA        = (float*)alloc((size_t)N_NODES * NCLASS * 4);
    float*  fB        = (float*)alloc((size_t)N_NODES * NCLASS * 4);
    int*    counts    = (int*)alloc((size_t)N_NODES * 4);
    int*    partial   = (int*)alloc((size_t)N_NODES * 4);
    int*    row_start = (int*)alloc((size_t)(N_NODES + 1) * 4);
    int*    cursor    = (int*)alloc((size_t)N_NODES * 4);
    int*    blocksums = (int*)alloc(128 * 4);
    ushort* w2fh      = (ushort*)alloc((size_t)16 * 16 * 64 * 8 * 2);
    ushort* w2fl      = (ushort*)alloc((size_t)16 * 16 * 64 * 8 * 2);
    float*  W3t       = (float*)alloc((size_t)DEGREE * NHID * 4);
    int2*   sedge     = (int2*)alloc((size_t)NEDGE * 8);

    const int SCAN_BLOCKS = (N_NODES + 1023) / 1024;  // 98

    // CSR build
    hipMemsetAsync(counts, 0, (size_t)N_NODES * 4, stream);
    hist_kernel<<<2048, 256, 0, stream>>>(arows, counts, NEDGE);
    scan_blocks<<<SCAN_BLOCKS, 1024, 0, stream>>>(counts, partial, blocksums, N_NODES);
    scan_sums<<<1, 64, 0, stream>>>(blocksums, SCAN_BLOCKS);
    finalize_rows<<<(N_NODES + 255) / 256, 256, 0, stream>>>(partial, blocksums, row_start, cursor,
                                                             N_NODES, NEDGE);
    scatter_edges<<<2048, 256, 0, stream>>>(arows, acols, avals, cursor, sedge, NEDGE);

    // gating MLP
    w2frag_build<<<64, 256, 0, stream>>>(W2, w2fh, w2fl);
    w3t_build<<<(NHID * DEGREE + 255) / 256, 256, 0, stream>>>(W3, W3t);
    softmax_topk<<<(N_NODES + 3) / 4, 256, 0, stream>>>(g0, ranked, N_NODES);
    mlp_kernel<<<(N_NODES + TM - 1) / TM, 256, 0, stream>>>(ranked, W1, b1, w2fh, w2fl, b2,
                                                            W3t, b3, weight, N_NODES);

    // 8 chained spmm; hop 1 absorbs init, hop 8 absorbs log_softmax
    const int SPMM_BLOCKS = (N_NODES + 3) / 4;
    const float* xin = f_pred;
    float* bufs[2] = {fA, fB};
    for (int it = 0; it < DEGREE - 1; ++it) {
        float* y = bufs[it & 1];
        if (it == 0)
            spmm_fused<0><<<SPMM_BLOCKS, 256, 0, stream>>>(row_start, sedge, xin, y, weight,
                                                           out_ls, f_pred, 1, N_NODES);
        else if (it < DEGREE - 2)
            spmm_fused<1><<<SPMM_BLOCKS, 256, 0, stream>>>(row_start, sedge, xin, y, weight,
                                                           out_ls, nullptr, it + 1, N_NODES);
        else
            spmm_fused<2><<<SPMM_BLOCKS, 256, 0, stream>>>(row_start, sedge, xin, y, weight,
                                                           out_ls, nullptr, it + 1, N_NODES);
        xin = y;
    }
}